// Round 18
// baseline (262.903 us; speedup 1.0000x reference)
//
#include <hip/hip_runtime.h>
#include <hip/hip_bf16.h>

#define DEVFN __device__ __forceinline__

DEVFN float siluf(float x)     { return x / (1.f + __expf(-x)); }
DEVFN float softplusf(float x) { return fmaxf(x, 0.f) + log1pf(__expf(-fabsf(x))); }

// Native RNE fp32 -> bf16 (compiler emits v_cvt_pk_bf16_f32 for pairs).
DEVFN ushort f2bf(float f) {
    __bf16 h = (__bf16)f;
    return __builtin_bit_cast(ushort, h);
}

// DPP cross-lane add: x + lane_perm(x). 0x128=row_ror:8, 0x124=row_ror:4,
// 0x4E=quad_perm xor2, 0xB1=quad_perm xor1.
template<int CTRL>
DEVFN float dpp_addf(float x) {
    union { float f; int i; } a, r;
    a.f = x;
    r.i = __builtin_amdgcn_update_dpp(0, a.i, CTRL, 0xF, 0xF, true);
    return x + r.f;
}
DEVFN float sum16(float p) {
    p = dpp_addf<0x128>(p);
    p = dpp_addf<0x124>(p);
    p = dpp_addf<0x4E>(p);
    p = dpp_addf<0xB1>(p);
    return p;
}
DEVFN float sum4(float p) {
    p = dpp_addf<0x4E>(p);
    p = dpp_addf<0xB1>(p);
    return p;
}

typedef __bf16 bf16x8 __attribute__((ext_vector_type(8)));
typedef float  f32x4  __attribute__((ext_vector_type(4)));
typedef ushort us8    __attribute__((ext_vector_type(8)));

// ---------------------------------------------------------------------------
// bf16 MFMA NT GEMM: C(M,N) += A(M,K) * B^T(N,K); A,B k-contiguous.
// BM,BN in {64,128}. 256 threads = 4 waves (2x2); per-wave (BM/2)x(BN/2).
// XCD-aware bijective block swizzle (total grid % 8 == 0 required).
template<int BM, int BN, bool A_F32, bool B_F32>
__global__ __launch_bounds__(256) void mfma_gemm_nt(
    const void* __restrict__ Av, const void* __restrict__ Bv,
    float* __restrict__ C, int M, int N, int K,
    long long Abs, long long Bbs, long long Cbs)
{
    constexpr int MFR = BM / 32;
    constexpr int NFR = BN / 32;
    __shared__ __align__(16) ushort As[BM][40];
    __shared__ __align__(16) ushort Bs[BN][40];

    const int tid = threadIdx.x;
    const int gx = gridDim.x, gy = gridDim.y;
    const int orig = (blockIdx.z * gy + blockIdx.y) * gx + blockIdx.x;
    const int cpx = (gx * gy * gridDim.z) >> 3;
    const int swz = (orig & 7) * cpx + (orig >> 3);
    const int bx = swz % gx;
    const int byz = swz / gx;
    const int by = byz % gy;
    const int b  = byz / gy;
    const int m0 = bx * BM;
    const int n0 = by * BN;
    const int lane = tid & 63;
    const int wid  = tid >> 6;
    const int wr   = wid >> 1;
    const int wc   = wid & 1;
    const int fr   = lane & 15;
    const int kq   = lane >> 4;

    f32x4 acc[MFR][NFR];
    #pragma unroll
    for (int i = 0; i < MFR; ++i)
        #pragma unroll
        for (int j = 0; j < NFR; ++j)
            acc[i][j] = (f32x4){0.f, 0.f, 0.f, 0.f};

    const int arow = tid >> 1;
    const int kh   = (tid & 1) * 16;

    for (int kt = 0; kt < K; kt += 32) {
        if (kt) __syncthreads();
        if (BM == 128 || arow < BM) {
            const long long off = (long long)b * Abs + (long long)(m0 + arow) * K + kt + kh;
            us8 lo, hi;
            if (A_F32) {
                const float4* p = (const float4*)((const float*)Av + off);
                float4 v0 = p[0], v1 = p[1], v2 = p[2], v3 = p[3];
                lo = (us8){f2bf(v0.x), f2bf(v0.y), f2bf(v0.z), f2bf(v0.w),
                           f2bf(v1.x), f2bf(v1.y), f2bf(v1.z), f2bf(v1.w)};
                hi = (us8){f2bf(v2.x), f2bf(v2.y), f2bf(v2.z), f2bf(v2.w),
                           f2bf(v3.x), f2bf(v3.y), f2bf(v3.z), f2bf(v3.w)};
            } else {
                const us8* p = (const us8*)((const ushort*)Av + off);
                lo = p[0]; hi = p[1];
            }
            *(us8*)&As[arow][kh]     = lo;
            *(us8*)&As[arow][kh + 8] = hi;
        }
        if (BN == 128 || arow < BN) {
            const long long off = (long long)b * Bbs + (long long)(n0 + arow) * K + kt + kh;
            us8 lo, hi;
            if (B_F32) {
                const float4* p = (const float4*)((const float*)Bv + off);
                float4 v0 = p[0], v1 = p[1], v2 = p[2], v3 = p[3];
                lo = (us8){f2bf(v0.x), f2bf(v0.y), f2bf(v0.z), f2bf(v0.w),
                           f2bf(v1.x), f2bf(v1.y), f2bf(v1.z), f2bf(v1.w)};
                hi = (us8){f2bf(v2.x), f2bf(v2.y), f2bf(v2.z), f2bf(v2.w),
                           f2bf(v3.x), f2bf(v3.y), f2bf(v3.z), f2bf(v3.w)};
            } else {
                const us8* p = (const us8*)((const ushort*)Bv + off);
                lo = p[0]; hi = p[1];
            }
            *(us8*)&Bs[arow][kh]     = lo;
            *(us8*)&Bs[arow][kh + 8] = hi;
        }
        __syncthreads();

        bf16x8 af[MFR], bfv[NFR];
        #pragma unroll
        for (int mi = 0; mi < MFR; ++mi)
            af[mi] = *(const bf16x8*)&As[wr * (BM / 2) + mi * 16 + fr][kq * 8];
        #pragma unroll
        for (int ni = 0; ni < NFR; ++ni)
            bfv[ni] = *(const bf16x8*)&Bs[wc * (BN / 2) + ni * 16 + fr][kq * 8];
        #pragma unroll
        for (int mi = 0; mi < MFR; ++mi)
            #pragma unroll
            for (int ni = 0; ni < NFR; ++ni)
                acc[mi][ni] = __builtin_amdgcn_mfma_f32_16x16x32_bf16(
                    af[mi], bfv[ni], acc[mi][ni], 0, 0, 0);
    }

    #pragma unroll
    for (int mi = 0; mi < MFR; ++mi) {
        const int gm = m0 + wr * (BM / 2) + mi * 16 + kq * 4;
        #pragma unroll
        for (int ni = 0; ni < NFR; ++ni) {
            const int gn = n0 + wc * (BN / 2) + ni * 16 + fr;
            f32x4 v = acc[mi][ni];
            #pragma unroll
            for (int r = 0; r < 4; ++r)
                C[(long long)b * Cbs + (long long)(gm + r) * N + gn] = v[r];
        }
    }
}

// ---------------------------------------------------------------------------
// Gated transpose: y = (p + Dd*u) * silu(z), p/u/z (b, D, L) row-major,
// output yt (b, L, D) bf16. Grid (L/32, D/32, B).
__global__ __launch_bounds__(256) void transpose_gate_f32_bf16(
    const float* __restrict__ p, const float* __restrict__ u,
    const float* __restrict__ z, const float* __restrict__ Dp,
    ushort* __restrict__ yt, int D, int Lx,
    long long Pbs, long long Ubs)
{
    __shared__ float ts[32][33];
    const int l0 = blockIdx.x * 32, d0 = blockIdx.y * 32, b = blockIdx.z;
    const int tx = threadIdx.x & 31, ty = threadIdx.x >> 5;
    const float* pb = p + (size_t)b * Pbs + (size_t)d0 * Lx + l0;
    const float* ub = u + (size_t)b * Ubs + (size_t)d0 * Lx + l0;
    const float* zb = z + (size_t)b * Pbs + (size_t)d0 * Lx + l0;
    #pragma unroll
    for (int r = ty; r < 32; r += 8) {
        float Dd = Dp[d0 + r];
        float pv = pb[(size_t)r * Lx + tx];
        float uv = ub[(size_t)r * Lx + tx];
        float zv = zb[(size_t)r * Lx + tx];
        ts[r][tx] = (pv + Dd * uv) * siluf(zv);
    }
    __syncthreads();
    ushort* ytb = yt + ((size_t)b * Lx + l0) * D + d0;
    #pragma unroll
    for (int r = ty; r < 32; r += 8)
        ytb[(size_t)r * D + tx] = f2bf(ts[tx][r]);
}

// ---------------------------------------------------------------------------
// Generic tiled fp32 GEMM (small ops). Xld = row stride of X's leading dim.
template<bool BKC, bool OUTM, bool CLIP, bool BIAS>
__global__ __launch_bounds__(256) void gemm_kernel(
    const float* __restrict__ A, const float* __restrict__ X,
    const float* __restrict__ bias, float* __restrict__ C,
    int M, int N, int K, int Xld, long long Xbs, long long Cbs)
{
    __shared__ __align__(16) float As[16][68];
    __shared__ __align__(16) float Xs[16][68];
    const int m0 = blockIdx.x * 64;
    const int n0 = blockIdx.y * 64;
    const int b  = blockIdx.z;
    const float* Xb = X + (long long)b * Xbs;
    const int tid = threadIdx.x;
    const int te = tid & 15, tl = tid >> 4;
    float acc[4][4] = {};

    for (int k0 = 0; k0 < K; k0 += 16) {
        #pragma unroll
        for (int idx = tid; idx < 1024; idx += 256) {
            int e = idx >> 4, kk = idx & 15;
            int m = m0 + e, k = k0 + kk;
            As[kk][e] = (m < M && k < K) ? A[(long long)m * K + k] : 0.f;
        }
        if (BKC) {
            #pragma unroll
            for (int idx = tid; idx < 1024; idx += 256) {
                int n = idx >> 4, kk = idx & 15;
                int nn = n0 + n, k = k0 + kk;
                Xs[kk][n] = (nn < N && k < K) ? Xb[(long long)nn * Xld + k] : 0.f;
            }
        } else {
            #pragma unroll
            for (int idx = tid; idx < 1024; idx += 256) {
                int kk = idx >> 6, n = idx & 63;
                int nn = n0 + n, k = k0 + kk;
                Xs[kk][n] = (nn < N && k < K) ? Xb[(long long)k * Xld + nn] : 0.f;
            }
        }
        __syncthreads();
        #pragma unroll
        for (int kk = 0; kk < 16; ++kk) {
            float4 a4 = *reinterpret_cast<const float4*>(&As[kk][te * 4]);
            float4 x4 = *reinterpret_cast<const float4*>(&Xs[kk][tl * 4]);
            float av[4] = {a4.x, a4.y, a4.z, a4.w};
            float xv[4] = {x4.x, x4.y, x4.z, x4.w};
            #pragma unroll
            for (int i = 0; i < 4; ++i)
                #pragma unroll
                for (int j = 0; j < 4; ++j)
                    acc[i][j] += av[i] * xv[j];
        }
        __syncthreads();
    }

    #pragma unroll
    for (int i = 0; i < 4; ++i) {
        int m = m0 + te * 4 + i;
        if (m >= M) continue;
        float bv = BIAS ? bias[m] : 0.f;
        #pragma unroll
        for (int j = 0; j < 4; ++j) {
            int n = n0 + tl * 4 + j;
            if (n >= N) continue;
            float v = acc[i][j] + bv;
            if (CLIP) v = fminf(fmaxf(v, -6.f), 6.f);
            if (OUTM) C[(long long)b * Cbs + (long long)m * N + n] = v;
            else      C[(long long)b * Cbs + (long long)n * M + m] = v;
        }
    }
}

// ---------------------------------------------------------------------------
// Split-K xproj with transposed output: P[(b,ks)][l][e].
__global__ __launch_bounds__(256) void xprojT_splitk(
    const float* __restrict__ W, const float* __restrict__ X,
    float* __restrict__ P, int L, int K, int KS)
{
    __shared__ float Xs[16][68];
    __shared__ float Ws[16][100];
    const int l0 = blockIdx.x * 64;
    const int ks = blockIdx.y;
    const int b  = blockIdx.z;
    const int Kc = K / KS;
    const int tid = threadIdx.x;
    const int tl = (tid & 15) * 4;
    const int te = (tid >> 4) * 6;
    float acc[4][6] = {};
    const float* Xb = X + (size_t)b * K * L;

    for (int d0 = ks * Kc; d0 < (ks + 1) * Kc; d0 += 16) {
        #pragma unroll
        for (int o = tid; o < 1024; o += 256) {
            int dd = o >> 6, l = o & 63;
            Xs[dd][l] = Xb[(size_t)(d0 + dd) * L + l0 + l];
        }
        #pragma unroll
        for (int o = tid; o < 1536; o += 256) {
            int e = o >> 4, dd = o & 15;
            Ws[dd][e] = W[(size_t)e * K + d0 + dd];
        }
        __syncthreads();
        #pragma unroll
        for (int dd = 0; dd < 16; ++dd) {
            float4 x4 = *(const float4*)&Xs[dd][tl];
            float xv[4] = {x4.x, x4.y, x4.z, x4.w};
            float wv[6];
            #pragma unroll
            for (int j = 0; j < 6; ++j) wv[j] = Ws[dd][te + j];
            #pragma unroll
            for (int i = 0; i < 4; ++i)
                #pragma unroll
                for (int j = 0; j < 6; ++j)
                    acc[i][j] += xv[i] * wv[j];
        }
        __syncthreads();
    }

    float* Pz = P + ((size_t)(b * KS + ks) * L + l0) * 96;
    #pragma unroll
    for (int i = 0; i < 4; ++i)
        #pragma unroll
        for (int j = 0; j < 6; ++j)
            Pz[(size_t)(tl + i) * 96 + te + j] = acc[i][j];
}

__global__ __launch_bounds__(256) void reduce_splitk(
    const float* __restrict__ P, float* __restrict__ C, int slab, int KS)
{
    const int i4 = blockIdx.x * 256 + threadIdx.x;
    const int b  = blockIdx.y;
    if (i4 * 4 >= slab) return;
    const float* base = P + (size_t)b * KS * slab + (size_t)i4 * 4;
    float4 acc = make_float4(0.f, 0.f, 0.f, 0.f);
    for (int ks = 0; ks < KS; ++ks) {
        float4 v = *(const float4*)(base + (size_t)ks * slab);
        acc.x += v.x; acc.y += v.y; acc.z += v.z; acc.w += v.w;
    }
    *(float4*)(C + (size_t)b * slab + (size_t)i4 * 4) = acc;
}

// ---------------------------------------------------------------------------
// Vectorized causal depthwise conv W=4 + SiLU, 4 outputs/thread.
__global__ __launch_bounds__(256) void conv4_silu_kernel(
    const float* __restrict__ in, const float* __restrict__ w,
    const float* __restrict__ bias, float* __restrict__ out,
    int B, int D, int L, int IC)
{
    int idx = blockIdx.x * 256 + threadIdx.x;
    int nL4 = L >> 2;
    if (idx >= B * D * nL4) return;
    int l4 = (idx % nL4) * 4;
    int d  = (idx / nL4) % D;
    int b  = idx / (nL4 * D);
    const float* xp = in + ((size_t)b * IC + d) * L;
    float4 cur = *(const float4*)(xp + l4);
    float4 prev = make_float4(0.f, 0.f, 0.f, 0.f);
    if (l4) prev = *(const float4*)(xp + l4 - 4);
    const float4 wv = *(const float4*)(w + d * 4);
    float bv = bias[d];
    float y0 = bv + wv.x*prev.y + wv.y*prev.z + wv.z*prev.w + wv.w*cur.x;
    float y1 = bv + wv.x*prev.z + wv.y*prev.w + wv.z*cur.x  + wv.w*cur.y;
    float y2 = bv + wv.x*prev.w + wv.y*cur.x  + wv.z*cur.y  + wv.w*cur.z;
    float y3 = bv + wv.x*cur.x  + wv.y*cur.y  + wv.z*cur.z  + wv.w*cur.w;
    *(float4*)(out + ((size_t)b * D + d) * L + l4) =
        make_float4(siluf(y0), siluf(y1), siluf(y2), siluf(y3));
}

// ---------------------------------------------------------------------------
// Fused inner {conv W=2 + SiLU} + x_proj + dt. Reads raw mxz x-rows (b,128,L
// rows 0..63); writes mxconv (b,64,L), mxdblT (b,L,12), mdelta (b,64,L).
// Grid (L/64, B), 256 threads.
__global__ __launch_bounds__(256) void inner_xproj_dt_conv_kernel(
    const float* __restrict__ mxz, const float* __restrict__ cw,
    const float* __restrict__ cb, const float* __restrict__ xw,
    const float* __restrict__ dtw, float* __restrict__ mxconv,
    float* __restrict__ mxdblT, float* __restrict__ mdelta, int L)
{
    __shared__ float xs[64][65];
    __shared__ float xwl[12][64];
    __shared__ float dtl[64][4];
    __shared__ float xd[4][65];
    const int tid = threadIdx.x;
    const int l0 = blockIdx.x * 64;
    const int b  = blockIdx.y;

    {
        const int k = tid >> 2, seg = (tid & 3) * 16;
        const float* xp = mxz + ((size_t)b * 128 + k) * L + l0 + seg;
        float prevv = (l0 + seg > 0) ? xp[-1] : 0.f;
        float4 v0 = *(const float4*)(xp);
        float4 v1 = *(const float4*)(xp + 4);
        float4 v2 = *(const float4*)(xp + 8);
        float4 v3 = *(const float4*)(xp + 12);
        float vals[16] = {v0.x, v0.y, v0.z, v0.w, v1.x, v1.y, v1.z, v1.w,
                          v2.x, v2.y, v2.z, v2.w, v3.x, v3.y, v3.z, v3.w};
        const float w0 = cw[k * 2], w1 = cw[k * 2 + 1], bv = cb[k];
        float outv[16];
        #pragma unroll
        for (int t = 0; t < 16; ++t) {
            outv[t] = siluf(w0 * prevv + w1 * vals[t] + bv);
            prevv = vals[t];
        }
        #pragma unroll
        for (int t = 0; t < 16; ++t) xs[k][seg + t] = outv[t];
        float* op = mxconv + ((size_t)b * 64 + k) * L + l0 + seg;
        *(float4*)(op)      = make_float4(outv[0], outv[1], outv[2], outv[3]);
        *(float4*)(op + 4)  = make_float4(outv[4], outv[5], outv[6], outv[7]);
        *(float4*)(op + 8)  = make_float4(outv[8], outv[9], outv[10], outv[11]);
        *(float4*)(op + 12) = make_float4(outv[12], outv[13], outv[14], outv[15]);
    }
    if (tid < 768) xwl[tid / 64][tid % 64] = xw[tid];
    dtl[tid >> 2][tid & 3] = dtw[tid];
    __syncthreads();

    for (int o = tid; o < 768; o += 256) {
        int e = o >> 6, l = o & 63;
        float acc = 0.f;
        #pragma unroll
        for (int k = 0; k < 64; ++k) acc += xwl[e][k] * xs[k][l];
        mxdblT[((size_t)b * L + l0 + l) * 12 + e] = acc;
        if (e < 4) xd[e][l] = acc;
    }
    __syncthreads();

    for (int o = tid; o < 4096; o += 256) {
        int dch = o >> 6, l = o & 63;
        float acc = dtl[dch][0] * xd[0][l] + dtl[dch][1] * xd[1][l]
                  + dtl[dch][2] * xd[2][l] + dtl[dch][3] * xd[3][l];
        mdelta[((size_t)b * 64 + dch) * L + l0 + l] = acc;
    }
}

// ---------------------------------------------------------------------------
// Fused inner out_proj + outer dt projection + clip. Grid (L/64, Dch/64, B).
__global__ __launch_bounds__(256) void outproj_dt_kernel(
    const float* __restrict__ ym, const float* __restrict__ mow,
    const float* __restrict__ dtw, const float* __restrict__ dtb,
    float* __restrict__ delta, int L, int Dch)
{
    __shared__ float xs[64][68];
    __shared__ float ws[64][64];
    __shared__ float dts[64][68];
    __shared__ float As[16][68];
    const int tid = threadIdx.x;
    const int l0 = blockIdx.x * 64;
    const int m0 = blockIdx.y * 64;
    const int b  = blockIdx.z;

    for (int o = tid; o < 4096; o += 256) {
        int k = o >> 6, l = o & 63;
        xs[k][l] = ym[((size_t)b * 64 + k) * L + l0 + l];
        ws[k][l] = mow[o];
    }
    __syncthreads();

    for (int o = tid; o < 4096; o += 256) {
        int e = o >> 6, l = o & 63;
        float acc = 0.f;
        #pragma unroll
        for (int k = 0; k < 64; ++k) acc += ws[e][k] * xs[k][l];
        dts[e][l] = acc;
    }

    const int te = tid & 15, tl = tid >> 4;
    float acc[4][4] = {};
    for (int k0 = 0; k0 < 64; k0 += 16) {
        __syncthreads();
        for (int idx = tid; idx < 1024; idx += 256) {
            int e = idx >> 6, m = idx & 63;
            As[e][m] = dtw[(size_t)(m0 + m) * 64 + k0 + e];
        }
        __syncthreads();
        #pragma unroll
        for (int kk = 0; kk < 16; ++kk) {
            float4 a4 = *(const float4*)&As[kk][te * 4];
            float4 x4 = *(const float4*)&dts[k0 + kk][tl * 4];
            float av[4] = {a4.x, a4.y, a4.z, a4.w};
            float xv[4] = {x4.x, x4.y, x4.z, x4.w};
            #pragma unroll
            for (int i = 0; i < 4; ++i)
                #pragma unroll
                for (int j = 0; j < 4; ++j)
                    acc[i][j] += av[i] * xv[j];
        }
    }

    #pragma unroll
    for (int i = 0; i < 4; ++i) {
        int m = m0 + te * 4 + i;
        float bv = dtb[m];
        #pragma unroll
        for (int j = 0; j < 4; ++j) {
            float v = fminf(fmaxf(acc[i][j] + bv, -6.f), 6.f);
            delta[((size_t)b * Dch + m) * L + l0 + tl * 4 + j] = v;
        }
    }
}

// ---------------------------------------------------------------------------
// Outer selective scan v9: 64 chunks x 16 steps, 1024 threads (16 waves).
// Serial chains halved again vs v8; gate-free output p = sum s*C.
// Grid (Dch, B).
__global__ __launch_bounds__(1024) void scan_outer9_kernel(
    const float* __restrict__ delta, const float* __restrict__ u,
    const float* __restrict__ xdblT, const float* __restrict__ A_log,
    const float* __restrict__ dt_bias, float* __restrict__ y,
    int Dch, int L, long long Ybs)
{
    __shared__ float2 dtdu[64][18];    // [chunk][step] padded
    __shared__ float2 PS[16][66];      // [state][chunk] padded

    const int tid = threadIdx.x;
    const int b = blockIdx.y;
    const int d = blockIdx.x;
    const size_t rbase = ((size_t)b * Dch + d) * L;

    // phase 0: dt/dt*u for the row (1 l per thread)
    {
        float dval = delta[rbase + tid];
        float uval = u[rbase + tid];
        float dt = softplusf(dval + dt_bias[d]);
        dtdu[tid >> 4][tid & 15] = make_float2(dt, dt * uval);
    }
    __syncthreads();

    const int c = tid >> 4;            // chunk 0..63 (16 steps)
    const int n = tid & 15;            // state
    const float Adn = -__expf(A_log[d * 16 + n]);
    const float* brow = xdblT + ((size_t)b * L + (size_t)c * 16) * 96 + 64 + n;

    // phase 1: chunk-local scan
    float s = 0.f, sumdt = 0.f;
    for (int q = 0; q < 4; ++q) {
        #pragma unroll
        for (int t = 0; t < 4; ++t) {
            int l = q * 4 + t;
            float bv = brow[(size_t)l * 96];
            float2 dd = dtdu[c][l];
            float a = __expf(dd.x * Adn);
            s = fmaf(a, s, dd.y * bv);
            sumdt += dd.x;
        }
    }
    PS[n][c] = make_float2(__expf(sumdt * Adn), s);
    __syncthreads();

    // combine: chunk-initial state via serial fold over previous chunks
    float s0 = 0.f;
    for (int j = 0; j < c; ++j) {
        float2 ps = PS[n][j];
        s0 = fmaf(ps.x, s0, ps.y);
    }

    // phase 2: rescan with init, DPP-reduce over states, emit raw p
    {
        const size_t ybase = (size_t)b * Ybs + (size_t)d * L + (size_t)c * 16;
        float s2 = s0;
        for (int q = 0; q < 4; ++q) {
            float yv[4];
            #pragma unroll
            for (int t = 0; t < 4; ++t) {
                int l = q * 4 + t;
                float bv = brow[(size_t)l * 96];
                float cv = brow[(size_t)l * 96 + 16];
                float2 dd = dtdu[c][l];
                float a = __expf(dd.x * Adn);
                s2 = fmaf(a, s2, dd.y * bv);
                yv[t] = sum16(s2 * cv);
            }
            if (n == 0)
                *(float4*)(y + ybase + q * 4) = make_float4(yv[0], yv[1], yv[2], yv[3]);
        }
    }
}

// ---------------------------------------------------------------------------
// Inner selective scan v6: 64 chunks x 4 states; float4 dtdu reads (LDS
// padded [18] for alignment); gate kept here (low redundancy: 4 lanes).
__global__ __launch_bounds__(256) void scan_inner6_kernel(
    const float* __restrict__ mdelta, const float* __restrict__ mu,
    const float* __restrict__ mxz, const float* __restrict__ mxdblT,
    const float* __restrict__ mA_log, const float* __restrict__ mDp,
    const float* __restrict__ mdt_b, float* __restrict__ ym, int L)
{
    __shared__ __align__(16) float2 dtdu[64][18];
    __shared__ float2 PS[4][66];

    const int tid = threadIdx.x;
    const int b = blockIdx.y;
    const int d = blockIdx.x;
    const size_t base = ((size_t)b * 64 + d) * L;

    {
        const int l0 = tid * 4;
        float4 d4 = *(const float4*)(mdelta + base + l0);
        float4 u4 = *(const float4*)(mu + base + l0);
        float bias = mdt_b[d];
        float dv[4] = {d4.x, d4.y, d4.z, d4.w};
        float uv[4] = {u4.x, u4.y, u4.z, u4.w};
        #pragma unroll
        for (int t = 0; t < 4; ++t) {
            float dt = softplusf(dv[t] + bias);
            dtdu[tid >> 2][(tid & 3) * 4 + t] = make_float2(dt, dt * uv[t]);
        }
    }
    __syncthreads();

    const int c = tid >> 2;
    const int n = tid & 3;
    const float Adn = -__expf(mA_log[d * 4 + n]);
    const float* brow = mxdblT + ((size_t)b * L + (size_t)c * 16) * 12 + 4 + n;

    float s = 0.f, sumdt = 0.f;
    for (int q = 0; q < 4; ++q) {
        float4 dA = *(const float4*)&dtdu[c][q * 4];
        float4 dB = *(const float4*)&dtdu[c][q * 4 + 2];
        float dt_[4] = {dA.x, dA.z, dB.x, dB.z};
        float du_[4] = {dA.y, dA.w, dB.y, dB.w};
        #pragma unroll
        for (int t = 0; t < 4; ++t) {
            float bv = brow[(size_t)(q * 4 + t) * 12];
            float a = __expf(dt_[t] * Adn);
            s = fmaf(a, s, du_[t] * bv);
            sumdt += dt_[t];
        }
    }
    PS[n][c] = make_float2(__expf(sumdt * Adn), s);
    __syncthreads();

    float s0 = 0.f;
    for (int j = 0; j < c; ++j) {
        float2 ps = PS[n][j];
        s0 = fmaf(ps.x, s0, ps.y);
    }

    {
        const float* up = mu + base + c * 16;
        const float* zp = mxz + ((size_t)b * 128 + 64 + d) * L + c * 16;
        const float Dd = mDp[d];
        float s2 = s0;
        for (int q = 0; q < 4; ++q) {
            float4 dA = *(const float4*)&dtdu[c][q * 4];
            float4 dB = *(const float4*)&dtdu[c][q * 4 + 2];
            float dt_[4] = {dA.x, dA.z, dB.x, dB.z};
            float du_[4] = {dA.y, dA.w, dB.y, dB.w};
            float4 u4 = *(const float4*)(up + q * 4);
            float4 z4 = *(const float4*)(zp + q * 4);
            float uv[4] = {u4.x, u4.y, u4.z, u4.w};
            float zv[4] = {z4.x, z4.y, z4.z, z4.w};
            float yv[4];
            #pragma unroll
            for (int t = 0; t < 4; ++t) {
                int l = q * 4 + t;
                float bv = brow[(size_t)l * 12];
                float cv = brow[(size_t)l * 12 + 4];
                float a = __expf(dt_[t] * Adn);
                s2 = fmaf(a, s2, du_[t] * bv);
                float p = sum4(s2 * cv);
                yv[t] = (p + Dd * uv[t]) * siluf(zv[t]);
            }
            if (n == 0)
                *(float4*)(ym + base + c * 16 + q * 4) = make_float4(yv[0], yv[1], yv[2], yv[3]);
        }
    }
}

// ---------------------------------------------------------------------------
extern "C" void kernel_launch(void* const* d_in, const int* in_sizes, int n_in,
                              void* d_out, int out_size, void* d_ws, size_t ws_size,
                              hipStream_t stream)
{
    const float* h         = (const float*)d_in[0];
    const float* in_w      = (const float*)d_in[1];
    const float* conv_w    = (const float*)d_in[2];
    const float* conv_b    = (const float*)d_in[3];
    const float* xproj_w   = (const float*)d_in[4];
    const float* dt_out_w  = (const float*)d_in[5];
    const float* dt_out_b  = (const float*)d_in[6];
    const float* A_log     = (const float*)d_in[7];
    const float* Dp        = (const float*)d_in[8];
    const float* out_w     = (const float*)d_in[9];
    const float* m_in_w    = (const float*)d_in[10];
    const float* m_conv_w  = (const float*)d_in[11];
    const float* m_conv_b  = (const float*)d_in[12];
    const float* m_xproj_w = (const float*)d_in[13];
    const float* m_dt_w    = (const float*)d_in[14];
    const float* m_dt_b    = (const float*)d_in[15];
    const float* m_A_log   = (const float*)d_in[16];
    const float* m_Dp      = (const float*)d_in[17];
    const float* m_out_w   = (const float*)d_in[18];
    float* out = (float*)d_out;

    const int B = 2, L = 1024, dm = 1024, di = 2048;

    float* ws     = (float*)d_ws;
    float* xz     = ws;                              // B*4096*L (x-rows reused as p)
    float* xconv  = xz     + (size_t)B * 2 * di * L; // B*2048*L
    float* xdblT  = xconv  + (size_t)B * di * L;     // B*L*96 (l-major)
    float* mxz    = xdblT  + (size_t)B * 96 * L;     // B*128*L
    float* mxconv = mxz    + (size_t)B * 128 * L;    // B*64*L
    float* mxdblT = mxconv + (size_t)B * 64 * L;     // B*L*12 (l-major)
    float* mdelta = mxdblT + (size_t)B * 12 * L;     // B*64*L
    float* ym     = mdelta + (size_t)B * 64 * L;     // B*64*L
    float* dtm    = ym     + (size_t)B * 64 * L;     // B*64*L (unused)
    float* delta  = dtm    + (size_t)B * 64 * L;     // B*2048*L
    ushort* yt    = (ushort*)delta;                  // bf16 y^T (after scan)
    float* part   = delta;                           // split-K partials (early)

    dim3 blk(256);

    // 1. xz[b,e,l] = sum_d in_w[e,d]*h[b,l,d]   (bf16 MFMA NT, XCD-swizzled)
    mfma_gemm_nt<128, 128, true, true><<<dim3(4096 / 128, L / 128, B), blk, 0, stream>>>(
        in_w, h, xz, 2 * di, L, dm, 0LL, (long long)L * dm, (long long)2 * di * L);

    // 2. x = silu(causal_conv(xz[:, :di]))  (vectorized W=4)
    {
        int total = B * di * (L / 4);
        conv4_silu_kernel<<<dim3((total + 255) / 256), blk, 0, stream>>>(
            xz, conv_w, conv_b, xconv, B, di, L, 2 * di);
    }

    // 3. xdblT[b,l,e] = sum_d xproj_w[e,d]*xconv[b,d,l]  (split-K + reduce)
    {
        const int KS = 16;
        xprojT_splitk<<<dim3(L / 64, KS, B), blk, 0, stream>>>(
            xproj_w, xconv, part, L, di, KS);
        int slab = 96 * L;
        reduce_splitk<<<dim3((slab / 4 + 255) / 256, B), blk, 0, stream>>>(
            part, xdblT, slab, KS);
    }

    // 4. inner in_proj: mxz[b,e,l] = sum_k m_in_w[e,k]*xdblT[b,l,k] (k<64)
    gemm_kernel<true, true, false, false><<<dim3(2, 16, B), blk, 0, stream>>>(
        m_in_w, xdblT, nullptr, mxz, 128, L, 64, 96, (long long)96 * L, (long long)128 * L);

    // 5+6+7. fused inner conv+silu + x_proj + dt
    inner_xproj_dt_conv_kernel<<<dim3(L / 64, B), blk, 0, stream>>>(
        mxz, m_conv_w, m_conv_b, m_xproj_w, m_dt_w, mxconv, mxdblT, mdelta, L);

    // 8. inner selective scan -> ym
    scan_inner6_kernel<<<dim3(64, B), blk, 0, stream>>>(
        mdelta, mxconv, mxz, mxdblT, m_A_log, m_Dp, m_dt_b, ym, L);

    // 9+10. fused inner out_proj + dt projection + clip -> delta
    outproj_dt_kernel<<<dim3(L / 64, di / 64, B), blk, 0, stream>>>(
        ym, m_out_w, dt_out_w, dt_out_b, delta, L, di);

    // 11. outer selective scan v9 (1024 threads, 64 chunks) -> raw p into
    //     the dead x-rows of xz (fp32)
    scan_outer9_kernel<<<dim3(di, B), dim3(1024), 0, stream>>>(
        delta, xconv, xdblT, A_log, dt_out_b, xz, di, L, (long long)2 * di * L);

    // 11b. gated transpose: y = (p + D*u)*silu(z), p in xz x-rows, z in xz
    //      z-rows, u = xconv -> yt (b,L,di) bf16 in dead delta buffer.
    transpose_gate_f32_bf16<<<dim3(L / 32, di / 32, B), blk, 0, stream>>>(
        xz, xconv, xz + (size_t)di * L, Dp, yt, di, L,
        (long long)2 * di * L, (long long)di * L);

    // 12. out[(b,l),e] = sum_d yt[(b,l),d]*out_w[e,d]  (batch-merged M=2048,
    //     64x64 tiles -> 512 blocks = 2/CU for latency hiding; XCD-swizzled)
    mfma_gemm_nt<64, 64, false, true><<<dim3(B * L / 64, dm / 64, 1), blk, 0, stream>>>(
        yt, out_w, out, B * L, dm, di, 0LL, 0LL, 0LL);
}

// Round 19
// 253.873 us; speedup vs baseline: 1.0356x; 1.0356x over previous
//
#include <hip/hip_runtime.h>
#include <hip/hip_bf16.h>

#define DEVFN __device__ __forceinline__

DEVFN float siluf(float x)     { return x / (1.f + __expf(-x)); }
DEVFN float softplusf(float x) { return fmaxf(x, 0.f) + log1pf(__expf(-fabsf(x))); }

// Native RNE fp32 -> bf16 (compiler emits v_cvt_pk_bf16_f32 for pairs).
DEVFN ushort f2bf(float f) {
    __bf16 h = (__bf16)f;
    return __builtin_bit_cast(ushort, h);
}

// DPP cross-lane add: x + lane_perm(x). 0x128=row_ror:8, 0x124=row_ror:4,
// 0x4E=quad_perm xor2, 0xB1=quad_perm xor1.
template<int CTRL>
DEVFN float dpp_addf(float x) {
    union { float f; int i; } a, r;
    a.f = x;
    r.i = __builtin_amdgcn_update_dpp(0, a.i, CTRL, 0xF, 0xF, true);
    return x + r.f;
}
DEVFN float sum16(float p) {
    p = dpp_addf<0x128>(p);
    p = dpp_addf<0x124>(p);
    p = dpp_addf<0x4E>(p);
    p = dpp_addf<0xB1>(p);
    return p;
}
DEVFN float sum4(float p) {
    p = dpp_addf<0x4E>(p);
    p = dpp_addf<0xB1>(p);
    return p;
}

typedef __bf16 bf16x8 __attribute__((ext_vector_type(8)));
typedef float  f32x4  __attribute__((ext_vector_type(4)));
typedef ushort us8    __attribute__((ext_vector_type(8)));

// ---------------------------------------------------------------------------
// bf16 MFMA NT GEMM: C(M,N) += A(M,K) * B^T(N,K); A,B k-contiguous.
// BM,BN in {64,128}. 256 threads = 4 waves (2x2); per-wave (BM/2)x(BN/2).
// XCD-aware bijective block swizzle (total grid % 8 == 0 required).
template<int BM, int BN, bool A_F32, bool B_F32>
__global__ __launch_bounds__(256) void mfma_gemm_nt(
    const void* __restrict__ Av, const void* __restrict__ Bv,
    float* __restrict__ C, int M, int N, int K,
    long long Abs, long long Bbs, long long Cbs)
{
    constexpr int MFR = BM / 32;
    constexpr int NFR = BN / 32;
    __shared__ __align__(16) ushort As[BM][40];
    __shared__ __align__(16) ushort Bs[BN][40];

    const int tid = threadIdx.x;
    const int gx = gridDim.x, gy = gridDim.y;
    const int orig = (blockIdx.z * gy + blockIdx.y) * gx + blockIdx.x;
    const int cpx = (gx * gy * gridDim.z) >> 3;
    const int swz = (orig & 7) * cpx + (orig >> 3);
    const int bx = swz % gx;
    const int byz = swz / gx;
    const int by = byz % gy;
    const int b  = byz / gy;
    const int m0 = bx * BM;
    const int n0 = by * BN;
    const int lane = tid & 63;
    const int wid  = tid >> 6;
    const int wr   = wid >> 1;
    const int wc   = wid & 1;
    const int fr   = lane & 15;
    const int kq   = lane >> 4;

    f32x4 acc[MFR][NFR];
    #pragma unroll
    for (int i = 0; i < MFR; ++i)
        #pragma unroll
        for (int j = 0; j < NFR; ++j)
            acc[i][j] = (f32x4){0.f, 0.f, 0.f, 0.f};

    const int arow = tid >> 1;
    const int kh   = (tid & 1) * 16;

    for (int kt = 0; kt < K; kt += 32) {
        if (kt) __syncthreads();
        if (BM == 128 || arow < BM) {
            const long long off = (long long)b * Abs + (long long)(m0 + arow) * K + kt + kh;
            us8 lo, hi;
            if (A_F32) {
                const float4* p = (const float4*)((const float*)Av + off);
                float4 v0 = p[0], v1 = p[1], v2 = p[2], v3 = p[3];
                lo = (us8){f2bf(v0.x), f2bf(v0.y), f2bf(v0.z), f2bf(v0.w),
                           f2bf(v1.x), f2bf(v1.y), f2bf(v1.z), f2bf(v1.w)};
                hi = (us8){f2bf(v2.x), f2bf(v2.y), f2bf(v2.z), f2bf(v2.w),
                           f2bf(v3.x), f2bf(v3.y), f2bf(v3.z), f2bf(v3.w)};
            } else {
                const us8* p = (const us8*)((const ushort*)Av + off);
                lo = p[0]; hi = p[1];
            }
            *(us8*)&As[arow][kh]     = lo;
            *(us8*)&As[arow][kh + 8] = hi;
        }
        if (BN == 128 || arow < BN) {
            const long long off = (long long)b * Bbs + (long long)(n0 + arow) * K + kt + kh;
            us8 lo, hi;
            if (B_F32) {
                const float4* p = (const float4*)((const float*)Bv + off);
                float4 v0 = p[0], v1 = p[1], v2 = p[2], v3 = p[3];
                lo = (us8){f2bf(v0.x), f2bf(v0.y), f2bf(v0.z), f2bf(v0.w),
                           f2bf(v1.x), f2bf(v1.y), f2bf(v1.z), f2bf(v1.w)};
                hi = (us8){f2bf(v2.x), f2bf(v2.y), f2bf(v2.z), f2bf(v2.w),
                           f2bf(v3.x), f2bf(v3.y), f2bf(v3.z), f2bf(v3.w)};
            } else {
                const us8* p = (const us8*)((const ushort*)Bv + off);
                lo = p[0]; hi = p[1];
            }
            *(us8*)&Bs[arow][kh]     = lo;
            *(us8*)&Bs[arow][kh + 8] = hi;
        }
        __syncthreads();

        bf16x8 af[MFR], bfv[NFR];
        #pragma unroll
        for (int mi = 0; mi < MFR; ++mi)
            af[mi] = *(const bf16x8*)&As[wr * (BM / 2) + mi * 16 + fr][kq * 8];
        #pragma unroll
        for (int ni = 0; ni < NFR; ++ni)
            bfv[ni] = *(const bf16x8*)&Bs[wc * (BN / 2) + ni * 16 + fr][kq * 8];
        #pragma unroll
        for (int mi = 0; mi < MFR; ++mi)
            #pragma unroll
            for (int ni = 0; ni < NFR; ++ni)
                acc[mi][ni] = __builtin_amdgcn_mfma_f32_16x16x32_bf16(
                    af[mi], bfv[ni], acc[mi][ni], 0, 0, 0);
    }

    #pragma unroll
    for (int mi = 0; mi < MFR; ++mi) {
        const int gm = m0 + wr * (BM / 2) + mi * 16 + kq * 4;
        #pragma unroll
        for (int ni = 0; ni < NFR; ++ni) {
            const int gn = n0 + wc * (BN / 2) + ni * 16 + fr;
            f32x4 v = acc[mi][ni];
            #pragma unroll
            for (int r = 0; r < 4; ++r)
                C[(long long)b * Cbs + (long long)(gm + r) * N + gn] = v[r];
        }
    }
}

// ---------------------------------------------------------------------------
// Gated transpose: y = (p + Dd*u) * silu(z), p/u/z (b, D, L) row-major,
// output yt (b, L, D) bf16. Grid (L/32, D/32, B).
__global__ __launch_bounds__(256) void transpose_gate_f32_bf16(
    const float* __restrict__ p, const float* __restrict__ u,
    const float* __restrict__ z, const float* __restrict__ Dp,
    ushort* __restrict__ yt, int D, int Lx,
    long long Pbs, long long Ubs)
{
    __shared__ float ts[32][33];
    const int l0 = blockIdx.x * 32, d0 = blockIdx.y * 32, b = blockIdx.z;
    const int tx = threadIdx.x & 31, ty = threadIdx.x >> 5;
    const float* pb = p + (size_t)b * Pbs + (size_t)d0 * Lx + l0;
    const float* ub = u + (size_t)b * Ubs + (size_t)d0 * Lx + l0;
    const float* zb = z + (size_t)b * Pbs + (size_t)d0 * Lx + l0;
    #pragma unroll
    for (int r = ty; r < 32; r += 8) {
        float Dd = Dp[d0 + r];
        float pv = pb[(size_t)r * Lx + tx];
        float uv = ub[(size_t)r * Lx + tx];
        float zv = zb[(size_t)r * Lx + tx];
        ts[r][tx] = (pv + Dd * uv) * siluf(zv);
    }
    __syncthreads();
    ushort* ytb = yt + ((size_t)b * Lx + l0) * D + d0;
    #pragma unroll
    for (int r = ty; r < 32; r += 8)
        ytb[(size_t)r * D + tx] = f2bf(ts[tx][r]);
}

// ---------------------------------------------------------------------------
// Generic tiled fp32 GEMM (small ops). Xld = row stride of X's leading dim.
template<bool BKC, bool OUTM, bool CLIP, bool BIAS>
__global__ __launch_bounds__(256) void gemm_kernel(
    const float* __restrict__ A, const float* __restrict__ X,
    const float* __restrict__ bias, float* __restrict__ C,
    int M, int N, int K, int Xld, long long Xbs, long long Cbs)
{
    __shared__ __align__(16) float As[16][68];
    __shared__ __align__(16) float Xs[16][68];
    const int m0 = blockIdx.x * 64;
    const int n0 = blockIdx.y * 64;
    const int b  = blockIdx.z;
    const float* Xb = X + (long long)b * Xbs;
    const int tid = threadIdx.x;
    const int te = tid & 15, tl = tid >> 4;
    float acc[4][4] = {};

    for (int k0 = 0; k0 < K; k0 += 16) {
        #pragma unroll
        for (int idx = tid; idx < 1024; idx += 256) {
            int e = idx >> 4, kk = idx & 15;
            int m = m0 + e, k = k0 + kk;
            As[kk][e] = (m < M && k < K) ? A[(long long)m * K + k] : 0.f;
        }
        if (BKC) {
            #pragma unroll
            for (int idx = tid; idx < 1024; idx += 256) {
                int n = idx >> 4, kk = idx & 15;
                int nn = n0 + n, k = k0 + kk;
                Xs[kk][n] = (nn < N && k < K) ? Xb[(long long)nn * Xld + k] : 0.f;
            }
        } else {
            #pragma unroll
            for (int idx = tid; idx < 1024; idx += 256) {
                int kk = idx >> 6, n = idx & 63;
                int nn = n0 + n, k = k0 + kk;
                Xs[kk][n] = (nn < N && k < K) ? Xb[(long long)k * Xld + nn] : 0.f;
            }
        }
        __syncthreads();
        #pragma unroll
        for (int kk = 0; kk < 16; ++kk) {
            float4 a4 = *reinterpret_cast<const float4*>(&As[kk][te * 4]);
            float4 x4 = *reinterpret_cast<const float4*>(&Xs[kk][tl * 4]);
            float av[4] = {a4.x, a4.y, a4.z, a4.w};
            float xv[4] = {x4.x, x4.y, x4.z, x4.w};
            #pragma unroll
            for (int i = 0; i < 4; ++i)
                #pragma unroll
                for (int j = 0; j < 4; ++j)
                    acc[i][j] += av[i] * xv[j];
        }
        __syncthreads();
    }

    #pragma unroll
    for (int i = 0; i < 4; ++i) {
        int m = m0 + te * 4 + i;
        if (m >= M) continue;
        float bv = BIAS ? bias[m] : 0.f;
        #pragma unroll
        for (int j = 0; j < 4; ++j) {
            int n = n0 + tl * 4 + j;
            if (n >= N) continue;
            float v = acc[i][j] + bv;
            if (CLIP) v = fminf(fmaxf(v, -6.f), 6.f);
            if (OUTM) C[(long long)b * Cbs + (long long)m * N + n] = v;
            else      C[(long long)b * Cbs + (long long)n * M + m] = v;
        }
    }
}

// ---------------------------------------------------------------------------
// Split-K xproj with transposed output: P[(b,ks)][l][e].
__global__ __launch_bounds__(256) void xprojT_splitk(
    const float* __restrict__ W, const float* __restrict__ X,
    float* __restrict__ P, int L, int K, int KS)
{
    __shared__ float Xs[16][68];
    __shared__ float Ws[16][100];
    const int l0 = blockIdx.x * 64;
    const int ks = blockIdx.y;
    const int b  = blockIdx.z;
    const int Kc = K / KS;
    const int tid = threadIdx.x;
    const int tl = (tid & 15) * 4;
    const int te = (tid >> 4) * 6;
    float acc[4][6] = {};
    const float* Xb = X + (size_t)b * K * L;

    for (int d0 = ks * Kc; d0 < (ks + 1) * Kc; d0 += 16) {
        #pragma unroll
        for (int o = tid; o < 1024; o += 256) {
            int dd = o >> 6, l = o & 63;
            Xs[dd][l] = Xb[(size_t)(d0 + dd) * L + l0 + l];
        }
        #pragma unroll
        for (int o = tid; o < 1536; o += 256) {
            int e = o >> 4, dd = o & 15;
            Ws[dd][e] = W[(size_t)e * K + d0 + dd];
        }
        __syncthreads();
        #pragma unroll
        for (int dd = 0; dd < 16; ++dd) {
            float4 x4 = *(const float4*)&Xs[dd][tl];
            float xv[4] = {x4.x, x4.y, x4.z, x4.w};
            float wv[6];
            #pragma unroll
            for (int j = 0; j < 6; ++j) wv[j] = Ws[dd][te + j];
            #pragma unroll
            for (int i = 0; i < 4; ++i)
                #pragma unroll
                for (int j = 0; j < 6; ++j)
                    acc[i][j] += xv[i] * wv[j];
        }
        __syncthreads();
    }

    float* Pz = P + ((size_t)(b * KS + ks) * L + l0) * 96;
    #pragma unroll
    for (int i = 0; i < 4; ++i)
        #pragma unroll
        for (int j = 0; j < 6; ++j)
            Pz[(size_t)(tl + i) * 96 + te + j] = acc[i][j];
}

__global__ __launch_bounds__(256) void reduce_splitk(
    const float* __restrict__ P, float* __restrict__ C, int slab, int KS)
{
    const int i4 = blockIdx.x * 256 + threadIdx.x;
    const int b  = blockIdx.y;
    if (i4 * 4 >= slab) return;
    const float* base = P + (size_t)b * KS * slab + (size_t)i4 * 4;
    float4 acc = make_float4(0.f, 0.f, 0.f, 0.f);
    for (int ks = 0; ks < KS; ++ks) {
        float4 v = *(const float4*)(base + (size_t)ks * slab);
        acc.x += v.x; acc.y += v.y; acc.z += v.z; acc.w += v.w;
    }
    *(float4*)(C + (size_t)b * slab + (size_t)i4 * 4) = acc;
}

// ---------------------------------------------------------------------------
// Vectorized causal depthwise conv W=4 + SiLU, 4 outputs/thread.
__global__ __launch_bounds__(256) void conv4_silu_kernel(
    const float* __restrict__ in, const float* __restrict__ w,
    const float* __restrict__ bias, float* __restrict__ out,
    int B, int D, int L, int IC)
{
    int idx = blockIdx.x * 256 + threadIdx.x;
    int nL4 = L >> 2;
    if (idx >= B * D * nL4) return;
    int l4 = (idx % nL4) * 4;
    int d  = (idx / nL4) % D;
    int b  = idx / (nL4 * D);
    const float* xp = in + ((size_t)b * IC + d) * L;
    float4 cur = *(const float4*)(xp + l4);
    float4 prev = make_float4(0.f, 0.f, 0.f, 0.f);
    if (l4) prev = *(const float4*)(xp + l4 - 4);
    const float4 wv = *(const float4*)(w + d * 4);
    float bv = bias[d];
    float y0 = bv + wv.x*prev.y + wv.y*prev.z + wv.z*prev.w + wv.w*cur.x;
    float y1 = bv + wv.x*prev.z + wv.y*prev.w + wv.z*cur.x  + wv.w*cur.y;
    float y2 = bv + wv.x*prev.w + wv.y*cur.x  + wv.z*cur.y  + wv.w*cur.z;
    float y3 = bv + wv.x*cur.x  + wv.y*cur.y  + wv.z*cur.z  + wv.w*cur.w;
    *(float4*)(out + ((size_t)b * D + d) * L + l4) =
        make_float4(siluf(y0), siluf(y1), siluf(y2), siluf(y3));
}

// ---------------------------------------------------------------------------
// Fused inner {conv W=2 + SiLU} + x_proj + dt. Reads raw mxz x-rows (b,128,L
// rows 0..63); writes mxconv (b,64,L), mxdblT (b,L,12), mdelta (b,64,L).
// Grid (L/64, B), 256 threads.
__global__ __launch_bounds__(256) void inner_xproj_dt_conv_kernel(
    const float* __restrict__ mxz, const float* __restrict__ cw,
    const float* __restrict__ cb, const float* __restrict__ xw,
    const float* __restrict__ dtw, float* __restrict__ mxconv,
    float* __restrict__ mxdblT, float* __restrict__ mdelta, int L)
{
    __shared__ float xs[64][65];
    __shared__ float xwl[12][64];
    __shared__ float dtl[64][4];
    __shared__ float xd[4][65];
    const int tid = threadIdx.x;
    const int l0 = blockIdx.x * 64;
    const int b  = blockIdx.y;

    {
        const int k = tid >> 2, seg = (tid & 3) * 16;
        const float* xp = mxz + ((size_t)b * 128 + k) * L + l0 + seg;
        float prevv = (l0 + seg > 0) ? xp[-1] : 0.f;
        float4 v0 = *(const float4*)(xp);
        float4 v1 = *(const float4*)(xp + 4);
        float4 v2 = *(const float4*)(xp + 8);
        float4 v3 = *(const float4*)(xp + 12);
        float vals[16] = {v0.x, v0.y, v0.z, v0.w, v1.x, v1.y, v1.z, v1.w,
                          v2.x, v2.y, v2.z, v2.w, v3.x, v3.y, v3.z, v3.w};
        const float w0 = cw[k * 2], w1 = cw[k * 2 + 1], bv = cb[k];
        float outv[16];
        #pragma unroll
        for (int t = 0; t < 16; ++t) {
            outv[t] = siluf(w0 * prevv + w1 * vals[t] + bv);
            prevv = vals[t];
        }
        #pragma unroll
        for (int t = 0; t < 16; ++t) xs[k][seg + t] = outv[t];
        float* op = mxconv + ((size_t)b * 64 + k) * L + l0 + seg;
        *(float4*)(op)      = make_float4(outv[0], outv[1], outv[2], outv[3]);
        *(float4*)(op + 4)  = make_float4(outv[4], outv[5], outv[6], outv[7]);
        *(float4*)(op + 8)  = make_float4(outv[8], outv[9], outv[10], outv[11]);
        *(float4*)(op + 12) = make_float4(outv[12], outv[13], outv[14], outv[15]);
    }
    if (tid < 768) xwl[tid / 64][tid % 64] = xw[tid];
    dtl[tid >> 2][tid & 3] = dtw[tid];
    __syncthreads();

    for (int o = tid; o < 768; o += 256) {
        int e = o >> 6, l = o & 63;
        float acc = 0.f;
        #pragma unroll
        for (int k = 0; k < 64; ++k) acc += xwl[e][k] * xs[k][l];
        mxdblT[((size_t)b * L + l0 + l) * 12 + e] = acc;
        if (e < 4) xd[e][l] = acc;
    }
    __syncthreads();

    for (int o = tid; o < 4096; o += 256) {
        int dch = o >> 6, l = o & 63;
        float acc = dtl[dch][0] * xd[0][l] + dtl[dch][1] * xd[1][l]
                  + dtl[dch][2] * xd[2][l] + dtl[dch][3] * xd[3][l];
        mdelta[((size_t)b * 64 + dch) * L + l0 + l] = acc;
    }
}

// ---------------------------------------------------------------------------
// Fused inner out_proj + outer dt projection + clip. Grid (L/64, Dch/64, B).
__global__ __launch_bounds__(256) void outproj_dt_kernel(
    const float* __restrict__ ym, const float* __restrict__ mow,
    const float* __restrict__ dtw, const float* __restrict__ dtb,
    float* __restrict__ delta, int L, int Dch)
{
    __shared__ float xs[64][68];
    __shared__ float ws[64][64];
    __shared__ float dts[64][68];
    __shared__ float As[16][68];
    const int tid = threadIdx.x;
    const int l0 = blockIdx.x * 64;
    const int m0 = blockIdx.y * 64;
    const int b  = blockIdx.z;

    for (int o = tid; o < 4096; o += 256) {
        int k = o >> 6, l = o & 63;
        xs[k][l] = ym[((size_t)b * 64 + k) * L + l0 + l];
        ws[k][l] = mow[o];
    }
    __syncthreads();

    for (int o = tid; o < 4096; o += 256) {
        int e = o >> 6, l = o & 63;
        float acc = 0.f;
        #pragma unroll
        for (int k = 0; k < 64; ++k) acc += ws[e][k] * xs[k][l];
        dts[e][l] = acc;
    }

    const int te = tid & 15, tl = tid >> 4;
    float acc[4][4] = {};
    for (int k0 = 0; k0 < 64; k0 += 16) {
        __syncthreads();
        for (int idx = tid; idx < 1024; idx += 256) {
            int e = idx >> 6, m = idx & 63;
            As[e][m] = dtw[(size_t)(m0 + m) * 64 + k0 + e];
        }
        __syncthreads();
        #pragma unroll
        for (int kk = 0; kk < 16; ++kk) {
            float4 a4 = *(const float4*)&As[kk][te * 4];
            float4 x4 = *(const float4*)&dts[k0 + kk][tl * 4];
            float av[4] = {a4.x, a4.y, a4.z, a4.w};
            float xv[4] = {x4.x, x4.y, x4.z, x4.w};
            #pragma unroll
            for (int i = 0; i < 4; ++i)
                #pragma unroll
                for (int j = 0; j < 4; ++j)
                    acc[i][j] += av[i] * xv[j];
        }
    }

    #pragma unroll
    for (int i = 0; i < 4; ++i) {
        int m = m0 + te * 4 + i;
        float bv = dtb[m];
        #pragma unroll
        for (int j = 0; j < 4; ++j) {
            float v = fminf(fmaxf(acc[i][j] + bv, -6.f), 6.f);
            delta[((size_t)b * Dch + m) * L + l0 + tl * 4 + j] = v;
        }
    }
}

// ---------------------------------------------------------------------------
// Outer selective scan v8 (best measured): 32 chunks x 16 states, 512
// threads (8 waves); gate-free output p = sum s*C. Grid (Dch, B).
__global__ __launch_bounds__(512) void scan_outer8_kernel(
    const float* __restrict__ delta, const float* __restrict__ u,
    const float* __restrict__ xdblT, const float* __restrict__ A_log,
    const float* __restrict__ dt_bias, float* __restrict__ y,
    int Dch, int L, long long Ybs)
{
    __shared__ float2 dtdu[32][34];    // [chunk][step] padded
    __shared__ float2 PS[16][33];      // [state][chunk] padded

    const int tid = threadIdx.x;
    const int b = blockIdx.y;
    const int d = blockIdx.x;
    const size_t rbase = ((size_t)b * Dch + d) * L;

    // phase 0: dt/dt*u for the row (2 l's per thread)
    {
        const int l0 = tid * 2;
        float2 d2 = *(const float2*)(delta + rbase + l0);
        float2 u2 = *(const float2*)(u + rbase + l0);
        float bias = dt_bias[d];
        float dv[2] = {d2.x, d2.y};
        float uv[2] = {u2.x, u2.y};
        #pragma unroll
        for (int t = 0; t < 2; ++t) {
            float dt = softplusf(dv[t] + bias);
            dtdu[l0 >> 5][(l0 & 31) + t] = make_float2(dt, dt * uv[t]);
        }
    }
    __syncthreads();

    const int c = tid >> 4;            // chunk 0..31 (32 steps)
    const int n = tid & 15;            // state
    const float Adn = -__expf(A_log[d * 16 + n]);
    const float* brow = xdblT + ((size_t)b * L + (size_t)c * 32) * 96 + 64 + n;

    // phase 1: chunk-local scan
    float s = 0.f, sumdt = 0.f;
    for (int q = 0; q < 8; ++q) {
        #pragma unroll
        for (int t = 0; t < 4; ++t) {
            int l = q * 4 + t;
            float bv = brow[(size_t)l * 96];
            float2 dd = dtdu[c][l];
            float a = __expf(dd.x * Adn);
            s = fmaf(a, s, dd.y * bv);
            sumdt += dd.x;
        }
    }
    PS[n][c] = make_float2(__expf(sumdt * Adn), s);
    __syncthreads();

    // combine: chunk-initial state via serial fold over previous chunks
    float s0 = 0.f;
    for (int j = 0; j < c; ++j) {
        float2 ps = PS[n][j];
        s0 = fmaf(ps.x, s0, ps.y);
    }

    // phase 2: rescan with init, DPP-reduce over states, emit raw p
    {
        const size_t ybase = (size_t)b * Ybs + (size_t)d * L + (size_t)c * 32;
        float s2 = s0;
        for (int q = 0; q < 8; ++q) {
            float yv[4];
            #pragma unroll
            for (int t = 0; t < 4; ++t) {
                int l = q * 4 + t;
                float bv = brow[(size_t)l * 96];
                float cv = brow[(size_t)l * 96 + 16];
                float2 dd = dtdu[c][l];
                float a = __expf(dd.x * Adn);
                s2 = fmaf(a, s2, dd.y * bv);
                yv[t] = sum16(s2 * cv);
            }
            if (n == 0)
                *(float4*)(y + ybase + q * 4) = make_float4(yv[0], yv[1], yv[2], yv[3]);
        }
    }
}

// ---------------------------------------------------------------------------
// Inner selective scan v6: 64 chunks x 4 states; float4 dtdu reads (LDS
// padded [18] for alignment); gate kept here (low redundancy: 4 lanes).
__global__ __launch_bounds__(256) void scan_inner6_kernel(
    const float* __restrict__ mdelta, const float* __restrict__ mu,
    const float* __restrict__ mxz, const float* __restrict__ mxdblT,
    const float* __restrict__ mA_log, const float* __restrict__ mDp,
    const float* __restrict__ mdt_b, float* __restrict__ ym, int L)
{
    __shared__ __align__(16) float2 dtdu[64][18];
    __shared__ float2 PS[4][66];

    const int tid = threadIdx.x;
    const int b = blockIdx.y;
    const int d = blockIdx.x;
    const size_t base = ((size_t)b * 64 + d) * L;

    {
        const int l0 = tid * 4;
        float4 d4 = *(const float4*)(mdelta + base + l0);
        float4 u4 = *(const float4*)(mu + base + l0);
        float bias = mdt_b[d];
        float dv[4] = {d4.x, d4.y, d4.z, d4.w};
        float uv[4] = {u4.x, u4.y, u4.z, u4.w};
        #pragma unroll
        for (int t = 0; t < 4; ++t) {
            float dt = softplusf(dv[t] + bias);
            dtdu[tid >> 2][(tid & 3) * 4 + t] = make_float2(dt, dt * uv[t]);
        }
    }
    __syncthreads();

    const int c = tid >> 2;
    const int n = tid & 3;
    const float Adn = -__expf(mA_log[d * 4 + n]);
    const float* brow = mxdblT + ((size_t)b * L + (size_t)c * 16) * 12 + 4 + n;

    float s = 0.f, sumdt = 0.f;
    for (int q = 0; q < 4; ++q) {
        float4 dA = *(const float4*)&dtdu[c][q * 4];
        float4 dB = *(const float4*)&dtdu[c][q * 4 + 2];
        float dt_[4] = {dA.x, dA.z, dB.x, dB.z};
        float du_[4] = {dA.y, dA.w, dB.y, dB.w};
        #pragma unroll
        for (int t = 0; t < 4; ++t) {
            float bv = brow[(size_t)(q * 4 + t) * 12];
            float a = __expf(dt_[t] * Adn);
            s = fmaf(a, s, du_[t] * bv);
            sumdt += dt_[t];
        }
    }
    PS[n][c] = make_float2(__expf(sumdt * Adn), s);
    __syncthreads();

    float s0 = 0.f;
    for (int j = 0; j < c; ++j) {
        float2 ps = PS[n][j];
        s0 = fmaf(ps.x, s0, ps.y);
    }

    {
        const float* up = mu + base + c * 16;
        const float* zp = mxz + ((size_t)b * 128 + 64 + d) * L + c * 16;
        const float Dd = mDp[d];
        float s2 = s0;
        for (int q = 0; q < 4; ++q) {
            float4 dA = *(const float4*)&dtdu[c][q * 4];
            float4 dB = *(const float4*)&dtdu[c][q * 4 + 2];
            float dt_[4] = {dA.x, dA.z, dB.x, dB.z};
            float du_[4] = {dA.y, dA.w, dB.y, dB.w};
            float4 u4 = *(const float4*)(up + q * 4);
            float4 z4 = *(const float4*)(zp + q * 4);
            float uv[4] = {u4.x, u4.y, u4.z, u4.w};
            float zv[4] = {z4.x, z4.y, z4.z, z4.w};
            float yv[4];
            #pragma unroll
            for (int t = 0; t < 4; ++t) {
                int l = q * 4 + t;
                float bv = brow[(size_t)l * 12];
                float cv = brow[(size_t)l * 12 + 4];
                float a = __expf(dt_[t] * Adn);
                s2 = fmaf(a, s2, du_[t] * bv);
                float p = sum4(s2 * cv);
                yv[t] = (p + Dd * uv[t]) * siluf(zv[t]);
            }
            if (n == 0)
                *(float4*)(ym + base + c * 16 + q * 4) = make_float4(yv[0], yv[1], yv[2], yv[3]);
        }
    }
}

// ---------------------------------------------------------------------------
extern "C" void kernel_launch(void* const* d_in, const int* in_sizes, int n_in,
                              void* d_out, int out_size, void* d_ws, size_t ws_size,
                              hipStream_t stream)
{
    const float* h         = (const float*)d_in[0];
    const float* in_w      = (const float*)d_in[1];
    const float* conv_w    = (const float*)d_in[2];
    const float* conv_b    = (const float*)d_in[3];
    const float* xproj_w   = (const float*)d_in[4];
    const float* dt_out_w  = (const float*)d_in[5];
    const float* dt_out_b  = (const float*)d_in[6];
    const float* A_log     = (const float*)d_in[7];
    const float* Dp        = (const float*)d_in[8];
    const float* out_w     = (const float*)d_in[9];
    const float* m_in_w    = (const float*)d_in[10];
    const float* m_conv_w  = (const float*)d_in[11];
    const float* m_conv_b  = (const float*)d_in[12];
    const float* m_xproj_w = (const float*)d_in[13];
    const float* m_dt_w    = (const float*)d_in[14];
    const float* m_dt_b    = (const float*)d_in[15];
    const float* m_A_log   = (const float*)d_in[16];
    const float* m_Dp      = (const float*)d_in[17];
    const float* m_out_w   = (const float*)d_in[18];
    float* out = (float*)d_out;

    const int B = 2, L = 1024, dm = 1024, di = 2048;

    float* ws     = (float*)d_ws;
    float* xz     = ws;                              // B*4096*L (x-rows reused as p)
    float* xconv  = xz     + (size_t)B * 2 * di * L; // B*2048*L
    float* xdblT  = xconv  + (size_t)B * di * L;     // B*L*96 (l-major)
    float* mxz    = xdblT  + (size_t)B * 96 * L;     // B*128*L
    float* mxconv = mxz    + (size_t)B * 128 * L;    // B*64*L
    float* mxdblT = mxconv + (size_t)B * 64 * L;     // B*L*12 (l-major)
    float* mdelta = mxdblT + (size_t)B * 12 * L;     // B*64*L
    float* ym     = mdelta + (size_t)B * 64 * L;     // B*64*L
    float* dtm    = ym     + (size_t)B * 64 * L;     // B*64*L (unused)
    float* delta  = dtm    + (size_t)B * 64 * L;     // B*2048*L
    ushort* yt    = (ushort*)delta;                  // bf16 y^T (after scan)
    float* part   = delta;                           // split-K partials (early)

    dim3 blk(256);

    // 1. xz[b,e,l] = sum_d in_w[e,d]*h[b,l,d]   (bf16 MFMA NT, XCD-swizzled)
    mfma_gemm_nt<128, 128, true, true><<<dim3(4096 / 128, L / 128, B), blk, 0, stream>>>(
        in_w, h, xz, 2 * di, L, dm, 0LL, (long long)L * dm, (long long)2 * di * L);

    // 2. x = silu(causal_conv(xz[:, :di]))  (vectorized W=4)
    {
        int total = B * di * (L / 4);
        conv4_silu_kernel<<<dim3((total + 255) / 256), blk, 0, stream>>>(
            xz, conv_w, conv_b, xconv, B, di, L, 2 * di);
    }

    // 3. xdblT[b,l,e] = sum_d xproj_w[e,d]*xconv[b,d,l]  (split-K + reduce)
    {
        const int KS = 16;
        xprojT_splitk<<<dim3(L / 64, KS, B), blk, 0, stream>>>(
            xproj_w, xconv, part, L, di, KS);
        int slab = 96 * L;
        reduce_splitk<<<dim3((slab / 4 + 255) / 256, B), blk, 0, stream>>>(
            part, xdblT, slab, KS);
    }

    // 4. inner in_proj: mxz[b,e,l] = sum_k m_in_w[e,k]*xdblT[b,l,k] (k<64)
    gemm_kernel<true, true, false, false><<<dim3(2, 16, B), blk, 0, stream>>>(
        m_in_w, xdblT, nullptr, mxz, 128, L, 64, 96, (long long)96 * L, (long long)128 * L);

    // 5+6+7. fused inner conv+silu + x_proj + dt
    inner_xproj_dt_conv_kernel<<<dim3(L / 64, B), blk, 0, stream>>>(
        mxz, m_conv_w, m_conv_b, m_xproj_w, m_dt_w, mxconv, mxdblT, mdelta, L);

    // 8. inner selective scan -> ym
    scan_inner6_kernel<<<dim3(64, B), blk, 0, stream>>>(
        mdelta, mxconv, mxz, mxdblT, m_A_log, m_Dp, m_dt_b, ym, L);

    // 9+10. fused inner out_proj + dt projection + clip -> delta
    outproj_dt_kernel<<<dim3(L / 64, di / 64, B), blk, 0, stream>>>(
        ym, m_out_w, dt_out_w, dt_out_b, delta, L, di);

    // 11. outer selective scan v8 (512 threads, 32 chunks) -> raw p into the
    //     dead x-rows of xz (fp32)
    scan_outer8_kernel<<<dim3(di, B), dim3(512), 0, stream>>>(
        delta, xconv, xdblT, A_log, dt_out_b, xz, di, L, (long long)2 * di * L);

    // 11b. gated transpose: y = (p + D*u)*silu(z), p in xz x-rows, z in xz
    //      z-rows, u = xconv -> yt (b,L,di) bf16 in dead delta buffer.
    transpose_gate_f32_bf16<<<dim3(L / 32, di / 32, B), blk, 0, stream>>>(
        xz, xconv, xz + (size_t)di * L, Dp, yt, di, L,
        (long long)2 * di * L, (long long)di * L);

    // 12. out[(b,l),e] = sum_d yt[(b,l),d]*out_w[e,d]  (batch-merged M=2048,
    //     64x64 tiles -> 512 blocks = 2/CU for latency hiding; XCD-swizzled)
    mfma_gemm_nt<64, 64, false, true><<<dim3(B * L / 64, dm / 64, 1), blk, 0, stream>>>(
        yt, out_w, out, B * L, dm, di, 0LL, 0LL, 0LL);
}

// Round 20
// 245.083 us; speedup vs baseline: 1.0727x; 1.0359x over previous
//
#include <hip/hip_runtime.h>
#include <hip/hip_bf16.h>

#define DEVFN __device__ __forceinline__

DEVFN float siluf(float x)     { return x / (1.f + __expf(-x)); }
DEVFN float softplusf(float x) { return fmaxf(x, 0.f) + log1pf(__expf(-fabsf(x))); }

// Native RNE fp32 -> bf16 (compiler emits v_cvt_pk_bf16_f32 for pairs).
DEVFN ushort f2bf(float f) {
    __bf16 h = (__bf16)f;
    return __builtin_bit_cast(ushort, h);
}

// DPP cross-lane add: x + lane_perm(x). 0x128=row_ror:8, 0x124=row_ror:4,
// 0x4E=quad_perm xor2, 0xB1=quad_perm xor1.
template<int CTRL>
DEVFN float dpp_addf(float x) {
    union { float f; int i; } a, r;
    a.f = x;
    r.i = __builtin_amdgcn_update_dpp(0, a.i, CTRL, 0xF, 0xF, true);
    return x + r.f;
}
DEVFN float sum16(float p) {
    p = dpp_addf<0x128>(p);
    p = dpp_addf<0x124>(p);
    p = dpp_addf<0x4E>(p);
    p = dpp_addf<0xB1>(p);
    return p;
}
DEVFN float sum4(float p) {
    p = dpp_addf<0x4E>(p);
    p = dpp_addf<0xB1>(p);
    return p;
}

typedef __bf16 bf16x8 __attribute__((ext_vector_type(8)));
typedef float  f32x4  __attribute__((ext_vector_type(4)));
typedef ushort us8    __attribute__((ext_vector_type(8)));

// ---------------------------------------------------------------------------
// bf16 MFMA NT GEMM: C(M,N) += A(M,K) * B^T(N,K); A,B k-contiguous.
// BM,BN in {64,128}. 256 threads = 4 waves (2x2); per-wave (BM/2)x(BN/2).
// XCD-aware bijective block swizzle (total grid % 8 == 0 required).
template<int BM, int BN, bool A_F32, bool B_F32>
__global__ __launch_bounds__(256) void mfma_gemm_nt(
    const void* __restrict__ Av, const void* __restrict__ Bv,
    float* __restrict__ C, int M, int N, int K,
    long long Abs, long long Bbs, long long Cbs)
{
    constexpr int MFR = BM / 32;
    constexpr int NFR = BN / 32;
    __shared__ __align__(16) ushort As[BM][40];
    __shared__ __align__(16) ushort Bs[BN][40];

    const int tid = threadIdx.x;
    const int gx = gridDim.x, gy = gridDim.y;
    const int orig = (blockIdx.z * gy + blockIdx.y) * gx + blockIdx.x;
    const int cpx = (gx * gy * gridDim.z) >> 3;
    const int swz = (orig & 7) * cpx + (orig >> 3);
    const int bx = swz % gx;
    const int byz = swz / gx;
    const int by = byz % gy;
    const int b  = byz / gy;
    const int m0 = bx * BM;
    const int n0 = by * BN;
    const int lane = tid & 63;
    const int wid  = tid >> 6;
    const int wr   = wid >> 1;
    const int wc   = wid & 1;
    const int fr   = lane & 15;
    const int kq   = lane >> 4;

    f32x4 acc[MFR][NFR];
    #pragma unroll
    for (int i = 0; i < MFR; ++i)
        #pragma unroll
        for (int j = 0; j < NFR; ++j)
            acc[i][j] = (f32x4){0.f, 0.f, 0.f, 0.f};

    const int arow = tid >> 1;
    const int kh   = (tid & 1) * 16;

    for (int kt = 0; kt < K; kt += 32) {
        if (kt) __syncthreads();
        if (BM == 128 || arow < BM) {
            const long long off = (long long)b * Abs + (long long)(m0 + arow) * K + kt + kh;
            us8 lo, hi;
            if (A_F32) {
                const float4* p = (const float4*)((const float*)Av + off);
                float4 v0 = p[0], v1 = p[1], v2 = p[2], v3 = p[3];
                lo = (us8){f2bf(v0.x), f2bf(v0.y), f2bf(v0.z), f2bf(v0.w),
                           f2bf(v1.x), f2bf(v1.y), f2bf(v1.z), f2bf(v1.w)};
                hi = (us8){f2bf(v2.x), f2bf(v2.y), f2bf(v2.z), f2bf(v2.w),
                           f2bf(v3.x), f2bf(v3.y), f2bf(v3.z), f2bf(v3.w)};
            } else {
                const us8* p = (const us8*)((const ushort*)Av + off);
                lo = p[0]; hi = p[1];
            }
            *(us8*)&As[arow][kh]     = lo;
            *(us8*)&As[arow][kh + 8] = hi;
        }
        if (BN == 128 || arow < BN) {
            const long long off = (long long)b * Bbs + (long long)(n0 + arow) * K + kt + kh;
            us8 lo, hi;
            if (B_F32) {
                const float4* p = (const float4*)((const float*)Bv + off);
                float4 v0 = p[0], v1 = p[1], v2 = p[2], v3 = p[3];
                lo = (us8){f2bf(v0.x), f2bf(v0.y), f2bf(v0.z), f2bf(v0.w),
                           f2bf(v1.x), f2bf(v1.y), f2bf(v1.z), f2bf(v1.w)};
                hi = (us8){f2bf(v2.x), f2bf(v2.y), f2bf(v2.z), f2bf(v2.w),
                           f2bf(v3.x), f2bf(v3.y), f2bf(v3.z), f2bf(v3.w)};
            } else {
                const us8* p = (const us8*)((const ushort*)Bv + off);
                lo = p[0]; hi = p[1];
            }
            *(us8*)&Bs[arow][kh]     = lo;
            *(us8*)&Bs[arow][kh + 8] = hi;
        }
        __syncthreads();

        bf16x8 af[MFR], bfv[NFR];
        #pragma unroll
        for (int mi = 0; mi < MFR; ++mi)
            af[mi] = *(const bf16x8*)&As[wr * (BM / 2) + mi * 16 + fr][kq * 8];
        #pragma unroll
        for (int ni = 0; ni < NFR; ++ni)
            bfv[ni] = *(const bf16x8*)&Bs[wc * (BN / 2) + ni * 16 + fr][kq * 8];
        #pragma unroll
        for (int mi = 0; mi < MFR; ++mi)
            #pragma unroll
            for (int ni = 0; ni < NFR; ++ni)
                acc[mi][ni] = __builtin_amdgcn_mfma_f32_16x16x32_bf16(
                    af[mi], bfv[ni], acc[mi][ni], 0, 0, 0);
    }

    #pragma unroll
    for (int mi = 0; mi < MFR; ++mi) {
        const int gm = m0 + wr * (BM / 2) + mi * 16 + kq * 4;
        #pragma unroll
        for (int ni = 0; ni < NFR; ++ni) {
            const int gn = n0 + wc * (BN / 2) + ni * 16 + fr;
            f32x4 v = acc[mi][ni];
            #pragma unroll
            for (int r = 0; r < 4; ++r)
                C[(long long)b * Cbs + (long long)(gm + r) * N + gn] = v[r];
        }
    }
}

// ---------------------------------------------------------------------------
// Split-K bf16 MFMA NT GEMM (single batch): P[ks][m][n] = partial over
// K-chunk ks. A bf16 (M,K), B f32 (N,K). BM=BN=64. Grid (M/64, N/64, KS).
__global__ __launch_bounds__(256) void mfma_gemm_nt_sk(
    const ushort* __restrict__ Av, const float* __restrict__ Bv,
    float* __restrict__ P, int M, int N, int K, int KS)
{
    constexpr int BM = 64, BN = 64;
    __shared__ __align__(16) ushort As[BM][40];
    __shared__ __align__(16) ushort Bs[BN][40];

    const int tid = threadIdx.x;
    const int gx = gridDim.x, gy = gridDim.y;
    const int orig = (blockIdx.z * gy + blockIdx.y) * gx + blockIdx.x;
    const int cpx = (gx * gy * gridDim.z) >> 3;
    const int swz = (orig & 7) * cpx + (orig >> 3);
    const int bx = swz % gx;
    const int byz = swz / gx;
    const int by = byz % gy;
    const int ks = byz / gy;
    const int m0 = bx * BM;
    const int n0 = by * BN;
    const int Kc = K / KS;
    const int lane = tid & 63;
    const int wid  = tid >> 6;
    const int wr   = wid >> 1;
    const int wc   = wid & 1;
    const int fr   = lane & 15;
    const int kq   = lane >> 4;

    f32x4 acc[2][2];
    #pragma unroll
    for (int i = 0; i < 2; ++i)
        #pragma unroll
        for (int j = 0; j < 2; ++j)
            acc[i][j] = (f32x4){0.f, 0.f, 0.f, 0.f};

    const int arow = tid >> 1;
    const int kh   = (tid & 1) * 16;

    for (int kt = ks * Kc; kt < (ks + 1) * Kc; kt += 32) {
        if (kt != ks * Kc) __syncthreads();
        if (arow < BM) {
            const us8* p = (const us8*)(Av + (long long)(m0 + arow) * K + kt + kh);
            *(us8*)&As[arow][kh]     = p[0];
            *(us8*)&As[arow][kh + 8] = p[1];
        } else {
            const int brow = arow - BM;
            const float4* p = (const float4*)(Bv + (long long)(n0 + brow) * K + kt + kh);
            float4 v0 = p[0], v1 = p[1], v2 = p[2], v3 = p[3];
            us8 lo = (us8){f2bf(v0.x), f2bf(v0.y), f2bf(v0.z), f2bf(v0.w),
                           f2bf(v1.x), f2bf(v1.y), f2bf(v1.z), f2bf(v1.w)};
            us8 hi = (us8){f2bf(v2.x), f2bf(v2.y), f2bf(v2.z), f2bf(v2.w),
                           f2bf(v3.x), f2bf(v3.y), f2bf(v3.z), f2bf(v3.w)};
            *(us8*)&Bs[brow][kh]     = lo;
            *(us8*)&Bs[brow][kh + 8] = hi;
        }
        __syncthreads();

        bf16x8 af[2], bfv[2];
        #pragma unroll
        for (int mi = 0; mi < 2; ++mi)
            af[mi] = *(const bf16x8*)&As[wr * 32 + mi * 16 + fr][kq * 8];
        #pragma unroll
        for (int ni = 0; ni < 2; ++ni)
            bfv[ni] = *(const bf16x8*)&Bs[wc * 32 + ni * 16 + fr][kq * 8];
        #pragma unroll
        for (int mi = 0; mi < 2; ++mi)
            #pragma unroll
            for (int ni = 0; ni < 2; ++ni)
                acc[mi][ni] = __builtin_amdgcn_mfma_f32_16x16x32_bf16(
                    af[mi], bfv[ni], acc[mi][ni], 0, 0, 0);
    }

    float* Pz = P + (long long)ks * M * N;
    #pragma unroll
    for (int mi = 0; mi < 2; ++mi) {
        const int gm = m0 + wr * 32 + mi * 16 + kq * 4;
        #pragma unroll
        for (int ni = 0; ni < 2; ++ni) {
            const int gn = n0 + wc * 32 + ni * 16 + fr;
            f32x4 v = acc[mi][ni];
            #pragma unroll
            for (int r = 0; r < 4; ++r)
                Pz[(long long)(gm + r) * N + gn] = v[r];
        }
    }
}

// ---------------------------------------------------------------------------
// Gated transpose: y = (p + Dd*u) * silu(z), p/u/z (b, D, L) row-major,
// output yt (b, L, D) bf16. Grid (L/32, D/32, B).
__global__ __launch_bounds__(256) void transpose_gate_f32_bf16(
    const float* __restrict__ p, const float* __restrict__ u,
    const float* __restrict__ z, const float* __restrict__ Dp,
    ushort* __restrict__ yt, int D, int Lx,
    long long Pbs, long long Ubs)
{
    __shared__ float ts[32][33];
    const int l0 = blockIdx.x * 32, d0 = blockIdx.y * 32, b = blockIdx.z;
    const int tx = threadIdx.x & 31, ty = threadIdx.x >> 5;
    const float* pb = p + (size_t)b * Pbs + (size_t)d0 * Lx + l0;
    const float* ub = u + (size_t)b * Ubs + (size_t)d0 * Lx + l0;
    const float* zb = z + (size_t)b * Pbs + (size_t)d0 * Lx + l0;
    #pragma unroll
    for (int r = ty; r < 32; r += 8) {
        float Dd = Dp[d0 + r];
        float pv = pb[(size_t)r * Lx + tx];
        float uv = ub[(size_t)r * Lx + tx];
        float zv = zb[(size_t)r * Lx + tx];
        ts[r][tx] = (pv + Dd * uv) * siluf(zv);
    }
    __syncthreads();
    ushort* ytb = yt + ((size_t)b * Lx + l0) * D + d0;
    #pragma unroll
    for (int r = ty; r < 32; r += 8)
        ytb[(size_t)r * D + tx] = f2bf(ts[tx][r]);
}

// ---------------------------------------------------------------------------
// Generic tiled fp32 GEMM (small ops). Xld = row stride of X's leading dim.
template<bool BKC, bool OUTM, bool CLIP, bool BIAS>
__global__ __launch_bounds__(256) void gemm_kernel(
    const float* __restrict__ A, const float* __restrict__ X,
    const float* __restrict__ bias, float* __restrict__ C,
    int M, int N, int K, int Xld, long long Xbs, long long Cbs)
{
    __shared__ __align__(16) float As[16][68];
    __shared__ __align__(16) float Xs[16][68];
    const int m0 = blockIdx.x * 64;
    const int n0 = blockIdx.y * 64;
    const int b  = blockIdx.z;
    const float* Xb = X + (long long)b * Xbs;
    const int tid = threadIdx.x;
    const int te = tid & 15, tl = tid >> 4;
    float acc[4][4] = {};

    for (int k0 = 0; k0 < K; k0 += 16) {
        #pragma unroll
        for (int idx = tid; idx < 1024; idx += 256) {
            int e = idx >> 4, kk = idx & 15;
            int m = m0 + e, k = k0 + kk;
            As[kk][e] = (m < M && k < K) ? A[(long long)m * K + k] : 0.f;
        }
        if (BKC) {
            #pragma unroll
            for (int idx = tid; idx < 1024; idx += 256) {
                int n = idx >> 4, kk = idx & 15;
                int nn = n0 + n, k = k0 + kk;
                Xs[kk][n] = (nn < N && k < K) ? Xb[(long long)nn * Xld + k] : 0.f;
            }
        } else {
            #pragma unroll
            for (int idx = tid; idx < 1024; idx += 256) {
                int kk = idx >> 6, n = idx & 63;
                int nn = n0 + n, k = k0 + kk;
                Xs[kk][n] = (nn < N && k < K) ? Xb[(long long)k * Xld + nn] : 0.f;
            }
        }
        __syncthreads();
        #pragma unroll
        for (int kk = 0; kk < 16; ++kk) {
            float4 a4 = *reinterpret_cast<const float4*>(&As[kk][te * 4]);
            float4 x4 = *reinterpret_cast<const float4*>(&Xs[kk][tl * 4]);
            float av[4] = {a4.x, a4.y, a4.z, a4.w};
            float xv[4] = {x4.x, x4.y, x4.z, x4.w};
            #pragma unroll
            for (int i = 0; i < 4; ++i)
                #pragma unroll
                for (int j = 0; j < 4; ++j)
                    acc[i][j] += av[i] * xv[j];
        }
        __syncthreads();
    }

    #pragma unroll
    for (int i = 0; i < 4; ++i) {
        int m = m0 + te * 4 + i;
        if (m >= M) continue;
        float bv = BIAS ? bias[m] : 0.f;
        #pragma unroll
        for (int j = 0; j < 4; ++j) {
            int n = n0 + tl * 4 + j;
            if (n >= N) continue;
            float v = acc[i][j] + bv;
            if (CLIP) v = fminf(fmaxf(v, -6.f), 6.f);
            if (OUTM) C[(long long)b * Cbs + (long long)m * N + n] = v;
            else      C[(long long)b * Cbs + (long long)n * M + m] = v;
        }
    }
}

// ---------------------------------------------------------------------------
// Split-K xproj with transposed output: P[(b,ks)][l][e].
__global__ __launch_bounds__(256) void xprojT_splitk(
    const float* __restrict__ W, const float* __restrict__ X,
    float* __restrict__ P, int L, int K, int KS)
{
    __shared__ float Xs[16][68];
    __shared__ float Ws[16][100];
    const int l0 = blockIdx.x * 64;
    const int ks = blockIdx.y;
    const int b  = blockIdx.z;
    const int Kc = K / KS;
    const int tid = threadIdx.x;
    const int tl = (tid & 15) * 4;
    const int te = (tid >> 4) * 6;
    float acc[4][6] = {};
    const float* Xb = X + (size_t)b * K * L;

    for (int d0 = ks * Kc; d0 < (ks + 1) * Kc; d0 += 16) {
        #pragma unroll
        for (int o = tid; o < 1024; o += 256) {
            int dd = o >> 6, l = o & 63;
            Xs[dd][l] = Xb[(size_t)(d0 + dd) * L + l0 + l];
        }
        #pragma unroll
        for (int o = tid; o < 1536; o += 256) {
            int e = o >> 4, dd = o & 15;
            Ws[dd][e] = W[(size_t)e * K + d0 + dd];
        }
        __syncthreads();
        #pragma unroll
        for (int dd = 0; dd < 16; ++dd) {
            float4 x4 = *(const float4*)&Xs[dd][tl];
            float xv[4] = {x4.x, x4.y, x4.z, x4.w};
            float wv[6];
            #pragma unroll
            for (int j = 0; j < 6; ++j) wv[j] = Ws[dd][te + j];
            #pragma unroll
            for (int i = 0; i < 4; ++i)
                #pragma unroll
                for (int j = 0; j < 6; ++j)
                    acc[i][j] += xv[i] * wv[j];
        }
        __syncthreads();
    }

    float* Pz = P + ((size_t)(b * KS + ks) * L + l0) * 96;
    #pragma unroll
    for (int i = 0; i < 4; ++i)
        #pragma unroll
        for (int j = 0; j < 6; ++j)
            Pz[(size_t)(tl + i) * 96 + te + j] = acc[i][j];
}

__global__ __launch_bounds__(256) void reduce_splitk(
    const float* __restrict__ P, float* __restrict__ C, int slab, int KS)
{
    const int i4 = blockIdx.x * 256 + threadIdx.x;
    const int b  = blockIdx.y;
    if (i4 * 4 >= slab) return;
    const float* base = P + (size_t)b * KS * slab + (size_t)i4 * 4;
    float4 acc = make_float4(0.f, 0.f, 0.f, 0.f);
    for (int ks = 0; ks < KS; ++ks) {
        float4 v = *(const float4*)(base + (size_t)ks * slab);
        acc.x += v.x; acc.y += v.y; acc.z += v.z; acc.w += v.w;
    }
    *(float4*)(C + (size_t)b * slab + (size_t)i4 * 4) = acc;
}

// ---------------------------------------------------------------------------
// Vectorized causal depthwise conv W=4 + SiLU, 4 outputs/thread.
__global__ __launch_bounds__(256) void conv4_silu_kernel(
    const float* __restrict__ in, const float* __restrict__ w,
    const float* __restrict__ bias, float* __restrict__ out,
    int B, int D, int L, int IC)
{
    int idx = blockIdx.x * 256 + threadIdx.x;
    int nL4 = L >> 2;
    if (idx >= B * D * nL4) return;
    int l4 = (idx % nL4) * 4;
    int d  = (idx / nL4) % D;
    int b  = idx / (nL4 * D);
    const float* xp = in + ((size_t)b * IC + d) * L;
    float4 cur = *(const float4*)(xp + l4);
    float4 prev = make_float4(0.f, 0.f, 0.f, 0.f);
    if (l4) prev = *(const float4*)(xp + l4 - 4);
    const float4 wv = *(const float4*)(w + d * 4);
    float bv = bias[d];
    float y0 = bv + wv.x*prev.y + wv.y*prev.z + wv.z*prev.w + wv.w*cur.x;
    float y1 = bv + wv.x*prev.z + wv.y*prev.w + wv.z*cur.x  + wv.w*cur.y;
    float y2 = bv + wv.x*prev.w + wv.y*cur.x  + wv.z*cur.y  + wv.w*cur.z;
    float y3 = bv + wv.x*cur.x  + wv.y*cur.y  + wv.z*cur.z  + wv.w*cur.w;
    *(float4*)(out + ((size_t)b * D + d) * L + l4) =
        make_float4(siluf(y0), siluf(y1), siluf(y2), siluf(y3));
}

// ---------------------------------------------------------------------------
// Fused inner {conv W=2 + SiLU} + x_proj + dt. Reads raw mxz x-rows (b,128,L
// rows 0..63); writes mxconv (b,64,L), mxdblT (b,L,12), mdelta (b,64,L).
// Grid (L/64, B), 256 threads.
__global__ __launch_bounds__(256) void inner_xproj_dt_conv_kernel(
    const float* __restrict__ mxz, const float* __restrict__ cw,
    const float* __restrict__ cb, const float* __restrict__ xw,
    const float* __restrict__ dtw, float* __restrict__ mxconv,
    float* __restrict__ mxdblT, float* __restrict__ mdelta, int L)
{
    __shared__ float xs[64][65];
    __shared__ float xwl[12][64];
    __shared__ float dtl[64][4];
    __shared__ float xd[4][65];
    const int tid = threadIdx.x;
    const int l0 = blockIdx.x * 64;
    const int b  = blockIdx.y;

    {
        const int k = tid >> 2, seg = (tid & 3) * 16;
        const float* xp = mxz + ((size_t)b * 128 + k) * L + l0 + seg;
        float prevv = (l0 + seg > 0) ? xp[-1] : 0.f;
        float4 v0 = *(const float4*)(xp);
        float4 v1 = *(const float4*)(xp + 4);
        float4 v2 = *(const float4*)(xp + 8);
        float4 v3 = *(const float4*)(xp + 12);
        float vals[16] = {v0.x, v0.y, v0.z, v0.w, v1.x, v1.y, v1.z, v1.w,
                          v2.x, v2.y, v2.z, v2.w, v3.x, v3.y, v3.z, v3.w};
        const float w0 = cw[k * 2], w1 = cw[k * 2 + 1], bv = cb[k];
        float outv[16];
        #pragma unroll
        for (int t = 0; t < 16; ++t) {
            outv[t] = siluf(w0 * prevv + w1 * vals[t] + bv);
            prevv = vals[t];
        }
        #pragma unroll
        for (int t = 0; t < 16; ++t) xs[k][seg + t] = outv[t];
        float* op = mxconv + ((size_t)b * 64 + k) * L + l0 + seg;
        *(float4*)(op)      = make_float4(outv[0], outv[1], outv[2], outv[3]);
        *(float4*)(op + 4)  = make_float4(outv[4], outv[5], outv[6], outv[7]);
        *(float4*)(op + 8)  = make_float4(outv[8], outv[9], outv[10], outv[11]);
        *(float4*)(op + 12) = make_float4(outv[12], outv[13], outv[14], outv[15]);
    }
    if (tid < 768) xwl[tid / 64][tid % 64] = xw[tid];
    dtl[tid >> 2][tid & 3] = dtw[tid];
    __syncthreads();

    for (int o = tid; o < 768; o += 256) {
        int e = o >> 6, l = o & 63;
        float acc = 0.f;
        #pragma unroll
        for (int k = 0; k < 64; ++k) acc += xwl[e][k] * xs[k][l];
        mxdblT[((size_t)b * L + l0 + l) * 12 + e] = acc;
        if (e < 4) xd[e][l] = acc;
    }
    __syncthreads();

    for (int o = tid; o < 4096; o += 256) {
        int dch = o >> 6, l = o & 63;
        float acc = dtl[dch][0] * xd[0][l] + dtl[dch][1] * xd[1][l]
                  + dtl[dch][2] * xd[2][l] + dtl[dch][3] * xd[3][l];
        mdelta[((size_t)b * 64 + dch) * L + l0 + l] = acc;
    }
}

// ---------------------------------------------------------------------------
// Fused inner out_proj + outer dt projection + clip. Grid (L/64, Dch/64, B).
__global__ __launch_bounds__(256) void outproj_dt_kernel(
    const float* __restrict__ ym, const float* __restrict__ mow,
    const float* __restrict__ dtw, const float* __restrict__ dtb,
    float* __restrict__ delta, int L, int Dch)
{
    __shared__ float xs[64][68];
    __shared__ float ws[64][64];
    __shared__ float dts[64][68];
    __shared__ float As[16][68];
    const int tid = threadIdx.x;
    const int l0 = blockIdx.x * 64;
    const int m0 = blockIdx.y * 64;
    const int b  = blockIdx.z;

    for (int o = tid; o < 4096; o += 256) {
        int k = o >> 6, l = o & 63;
        xs[k][l] = ym[((size_t)b * 64 + k) * L + l0 + l];
        ws[k][l] = mow[o];
    }
    __syncthreads();

    for (int o = tid; o < 4096; o += 256) {
        int e = o >> 6, l = o & 63;
        float acc = 0.f;
        #pragma unroll
        for (int k = 0; k < 64; ++k) acc += ws[e][k] * xs[k][l];
        dts[e][l] = acc;
    }

    const int te = tid & 15, tl = tid >> 4;
    float acc[4][4] = {};
    for (int k0 = 0; k0 < 64; k0 += 16) {
        __syncthreads();
        for (int idx = tid; idx < 1024; idx += 256) {
            int e = idx >> 6, m = idx & 63;
            As[e][m] = dtw[(size_t)(m0 + m) * 64 + k0 + e];
        }
        __syncthreads();
        #pragma unroll
        for (int kk = 0; kk < 16; ++kk) {
            float4 a4 = *(const float4*)&As[kk][te * 4];
            float4 x4 = *(const float4*)&dts[k0 + kk][tl * 4];
            float av[4] = {a4.x, a4.y, a4.z, a4.w};
            float xv[4] = {x4.x, x4.y, x4.z, x4.w};
            #pragma unroll
            for (int i = 0; i < 4; ++i)
                #pragma unroll
                for (int j = 0; j < 4; ++j)
                    acc[i][j] += av[i] * xv[j];
        }
    }

    #pragma unroll
    for (int i = 0; i < 4; ++i) {
        int m = m0 + te * 4 + i;
        float bv = dtb[m];
        #pragma unroll
        for (int j = 0; j < 4; ++j) {
            float v = fminf(fmaxf(acc[i][j] + bv, -6.f), 6.f);
            delta[((size_t)b * Dch + m) * L + l0 + tl * 4 + j] = v;
        }
    }
}

// ---------------------------------------------------------------------------
// Outer selective scan v8 (best measured): 32 chunks x 16 states, 512
// threads (8 waves); gate-free output p = sum s*C. Grid (Dch, B).
__global__ __launch_bounds__(512) void scan_outer8_kernel(
    const float* __restrict__ delta, const float* __restrict__ u,
    const float* __restrict__ xdblT, const float* __restrict__ A_log,
    const float* __restrict__ dt_bias, float* __restrict__ y,
    int Dch, int L, long long Ybs)
{
    __shared__ float2 dtdu[32][34];
    __shared__ float2 PS[16][33];

    const int tid = threadIdx.x;
    const int b = blockIdx.y;
    const int d = blockIdx.x;
    const size_t rbase = ((size_t)b * Dch + d) * L;

    {
        const int l0 = tid * 2;
        float2 d2 = *(const float2*)(delta + rbase + l0);
        float2 u2 = *(const float2*)(u + rbase + l0);
        float bias = dt_bias[d];
        float dv[2] = {d2.x, d2.y};
        float uv[2] = {u2.x, u2.y};
        #pragma unroll
        for (int t = 0; t < 2; ++t) {
            float dt = softplusf(dv[t] + bias);
            dtdu[l0 >> 5][(l0 & 31) + t] = make_float2(dt, dt * uv[t]);
        }
    }
    __syncthreads();

    const int c = tid >> 4;
    const int n = tid & 15;
    const float Adn = -__expf(A_log[d * 16 + n]);
    const float* brow = xdblT + ((size_t)b * L + (size_t)c * 32) * 96 + 64 + n;

    float s = 0.f, sumdt = 0.f;
    for (int q = 0; q < 8; ++q) {
        #pragma unroll
        for (int t = 0; t < 4; ++t) {
            int l = q * 4 + t;
            float bv = brow[(size_t)l * 96];
            float2 dd = dtdu[c][l];
            float a = __expf(dd.x * Adn);
            s = fmaf(a, s, dd.y * bv);
            sumdt += dd.x;
        }
    }
    PS[n][c] = make_float2(__expf(sumdt * Adn), s);
    __syncthreads();

    float s0 = 0.f;
    for (int j = 0; j < c; ++j) {
        float2 ps = PS[n][j];
        s0 = fmaf(ps.x, s0, ps.y);
    }

    {
        const size_t ybase = (size_t)b * Ybs + (size_t)d * L + (size_t)c * 32;
        float s2 = s0;
        for (int q = 0; q < 8; ++q) {
            float yv[4];
            #pragma unroll
            for (int t = 0; t < 4; ++t) {
                int l = q * 4 + t;
                float bv = brow[(size_t)l * 96];
                float cv = brow[(size_t)l * 96 + 16];
                float2 dd = dtdu[c][l];
                float a = __expf(dd.x * Adn);
                s2 = fmaf(a, s2, dd.y * bv);
                yv[t] = sum16(s2 * cv);
            }
            if (n == 0)
                *(float4*)(y + ybase + q * 4) = make_float4(yv[0], yv[1], yv[2], yv[3]);
        }
    }
}

// ---------------------------------------------------------------------------
// Inner selective scan v6: 64 chunks x 4 states; float4 dtdu reads (LDS
// padded [18] for alignment); gate kept here (low redundancy: 4 lanes).
__global__ __launch_bounds__(256) void scan_inner6_kernel(
    const float* __restrict__ mdelta, const float* __restrict__ mu,
    const float* __restrict__ mxz, const float* __restrict__ mxdblT,
    const float* __restrict__ mA_log, const float* __restrict__ mDp,
    const float* __restrict__ mdt_b, float* __restrict__ ym, int L)
{
    __shared__ __align__(16) float2 dtdu[64][18];
    __shared__ float2 PS[4][66];

    const int tid = threadIdx.x;
    const int b = blockIdx.y;
    const int d = blockIdx.x;
    const size_t base = ((size_t)b * 64 + d) * L;

    {
        const int l0 = tid * 4;
        float4 d4 = *(const float4*)(mdelta + base + l0);
        float4 u4 = *(const float4*)(mu + base + l0);
        float bias = mdt_b[d];
        float dv[4] = {d4.x, d4.y, d4.z, d4.w};
        float uv[4] = {u4.x, u4.y, u4.z, u4.w};
        #pragma unroll
        for (int t = 0; t < 4; ++t) {
            float dt = softplusf(dv[t] + bias);
            dtdu[tid >> 2][(tid & 3) * 4 + t] = make_float2(dt, dt * uv[t]);
        }
    }
    __syncthreads();

    const int c = tid >> 2;
    const int n = tid & 3;
    const float Adn = -__expf(mA_log[d * 4 + n]);
    const float* brow = mxdblT + ((size_t)b * L + (size_t)c * 16) * 12 + 4 + n;

    float s = 0.f, sumdt = 0.f;
    for (int q = 0; q < 4; ++q) {
        float4 dA = *(const float4*)&dtdu[c][q * 4];
        float4 dB = *(const float4*)&dtdu[c][q * 4 + 2];
        float dt_[4] = {dA.x, dA.z, dB.x, dB.z};
        float du_[4] = {dA.y, dA.w, dB.y, dB.w};
        #pragma unroll
        for (int t = 0; t < 4; ++t) {
            float bv = brow[(size_t)(q * 4 + t) * 12];
            float a = __expf(dt_[t] * Adn);
            s = fmaf(a, s, du_[t] * bv);
            sumdt += dt_[t];
        }
    }
    PS[n][c] = make_float2(__expf(sumdt * Adn), s);
    __syncthreads();

    float s0 = 0.f;
    for (int j = 0; j < c; ++j) {
        float2 ps = PS[n][j];
        s0 = fmaf(ps.x, s0, ps.y);
    }

    {
        const float* up = mu + base + c * 16;
        const float* zp = mxz + ((size_t)b * 128 + 64 + d) * L + c * 16;
        const float Dd = mDp[d];
        float s2 = s0;
        for (int q = 0; q < 4; ++q) {
            float4 dA = *(const float4*)&dtdu[c][q * 4];
            float4 dB = *(const float4*)&dtdu[c][q * 4 + 2];
            float dt_[4] = {dA.x, dA.z, dB.x, dB.z};
            float du_[4] = {dA.y, dA.w, dB.y, dB.w};
            float4 u4 = *(const float4*)(up + q * 4);
            float4 z4 = *(const float4*)(zp + q * 4);
            float uv[4] = {u4.x, u4.y, u4.z, u4.w};
            float zv[4] = {z4.x, z4.y, z4.z, z4.w};
            float yv[4];
            #pragma unroll
            for (int t = 0; t < 4; ++t) {
                int l = q * 4 + t;
                float bv = brow[(size_t)l * 12];
                float cv = brow[(size_t)l * 12 + 4];
                float a = __expf(dt_[t] * Adn);
                s2 = fmaf(a, s2, du_[t] * bv);
                float p = sum4(s2 * cv);
                yv[t] = (p + Dd * uv[t]) * siluf(zv[t]);
            }
            if (n == 0)
                *(float4*)(ym + base + c * 16 + q * 4) = make_float4(yv[0], yv[1], yv[2], yv[3]);
        }
    }
}

// ---------------------------------------------------------------------------
extern "C" void kernel_launch(void* const* d_in, const int* in_sizes, int n_in,
                              void* d_out, int out_size, void* d_ws, size_t ws_size,
                              hipStream_t stream)
{
    const float* h         = (const float*)d_in[0];
    const float* in_w      = (const float*)d_in[1];
    const float* conv_w    = (const float*)d_in[2];
    const float* conv_b    = (const float*)d_in[3];
    const float* xproj_w   = (const float*)d_in[4];
    const float* dt_out_w  = (const float*)d_in[5];
    const float* dt_out_b  = (const float*)d_in[6];
    const float* A_log     = (const float*)d_in[7];
    const float* Dp        = (const float*)d_in[8];
    const float* out_w     = (const float*)d_in[9];
    const float* m_in_w    = (const float*)d_in[10];
    const float* m_conv_w  = (const float*)d_in[11];
    const float* m_conv_b  = (const float*)d_in[12];
    const float* m_xproj_w = (const float*)d_in[13];
    const float* m_dt_w    = (const float*)d_in[14];
    const float* m_dt_b    = (const float*)d_in[15];
    const float* m_A_log   = (const float*)d_in[16];
    const float* m_Dp      = (const float*)d_in[17];
    const float* m_out_w   = (const float*)d_in[18];
    float* out = (float*)d_out;

    const int B = 2, L = 1024, dm = 1024, di = 2048;

    float* ws     = (float*)d_ws;
    float* xz     = ws;                              // B*4096*L (p, z; later SK partials)
    float* xconv  = xz     + (size_t)B * 2 * di * L; // B*2048*L
    float* xdblT  = xconv  + (size_t)B * di * L;     // B*L*96 (l-major)
    float* mxz    = xdblT  + (size_t)B * 96 * L;     // B*128*L
    float* mxconv = mxz    + (size_t)B * 128 * L;    // B*64*L
    float* mxdblT = mxconv + (size_t)B * 64 * L;     // B*L*12 (l-major)
    float* mdelta = mxdblT + (size_t)B * 12 * L;     // B*64*L
    float* ym     = mdelta + (size_t)B * 64 * L;     // B*64*L
    float* dtm    = ym     + (size_t)B * 64 * L;     // B*64*L (unused)
    float* delta  = dtm    + (size_t)B * 64 * L;     // B*2048*L
    ushort* yt    = (ushort*)delta;                  // bf16 y^T (after scan)
    float* part   = delta;                           // xproj split-K partials (early)

    dim3 blk(256);

    // 1. xz[b,e,l] = sum_d in_w[e,d]*h[b,l,d]   (bf16 MFMA NT, XCD-swizzled)
    mfma_gemm_nt<128, 128, true, true><<<dim3(4096 / 128, L / 128, B), blk, 0, stream>>>(
        in_w, h, xz, 2 * di, L, dm, 0LL, (long long)L * dm, (long long)2 * di * L);

    // 2. x = silu(causal_conv(xz[:, :di]))  (vectorized W=4)
    {
        int total = B * di * (L / 4);
        conv4_silu_kernel<<<dim3((total + 255) / 256), blk, 0, stream>>>(
            xz, conv_w, conv_b, xconv, B, di, L, 2 * di);
    }

    // 3. xdblT[b,l,e] = sum_d xproj_w[e,d]*xconv[b,d,l]  (split-K + reduce)
    {
        const int KS = 16;
        xprojT_splitk<<<dim3(L / 64, KS, B), blk, 0, stream>>>(
            xproj_w, xconv, part, L, di, KS);
        int slab = 96 * L;
        reduce_splitk<<<dim3((slab / 4 + 255) / 256, B), blk, 0, stream>>>(
            part, xdblT, slab, KS);
    }

    // 4. inner in_proj: mxz[b,e,l] = sum_k m_in_w[e,k]*xdblT[b,l,k] (k<64)
    gemm_kernel<true, true, false, false><<<dim3(2, 16, B), blk, 0, stream>>>(
        m_in_w, xdblT, nullptr, mxz, 128, L, 64, 96, (long long)96 * L, (long long)128 * L);

    // 5+6+7. fused inner conv+silu + x_proj + dt
    inner_xproj_dt_conv_kernel<<<dim3(L / 64, B), blk, 0, stream>>>(
        mxz, m_conv_w, m_conv_b, m_xproj_w, m_dt_w, mxconv, mxdblT, mdelta, L);

    // 8. inner selective scan -> ym
    scan_inner6_kernel<<<dim3(64, B), blk, 0, stream>>>(
        mdelta, mxconv, mxz, mxdblT, m_A_log, m_Dp, m_dt_b, ym, L);

    // 9+10. fused inner out_proj + dt projection + clip -> delta
    outproj_dt_kernel<<<dim3(L / 64, di / 64, B), blk, 0, stream>>>(
        ym, m_out_w, dt_out_w, dt_out_b, delta, L, di);

    // 11. outer selective scan v8 (512 threads, 32 chunks) -> raw p into the
    //     dead x-rows of xz (fp32)
    scan_outer8_kernel<<<dim3(di, B), dim3(512), 0, stream>>>(
        delta, xconv, xdblT, A_log, dt_out_b, xz, di, L, (long long)2 * di * L);

    // 11b. gated transpose: y = (p + D*u)*silu(z), p in xz x-rows, z in xz
    //      z-rows, u = xconv -> yt (b,L,di) bf16 in dead delta buffer.
    //      After this, xz is fully dead -> reused as out_proj SK partials.
    transpose_gate_f32_bf16<<<dim3(L / 32, di / 32, B), blk, 0, stream>>>(
        xz, xconv, xz + (size_t)di * L, Dp, yt, di, L,
        (long long)2 * di * L, (long long)di * L);

    // 12. out[(b,l),e] = sum_d yt[(b,l),d]*out_w[e,d]  (batch-merged M=2048,
    //     split-K=4 -> 2048 blocks (8/CU), partials in dead xz, then reduce)
    {
        const int KS = 4;
        float* gpart = xz;                           // 4 * 2048*1024 f32 = 32 MB
        mfma_gemm_nt_sk<<<dim3(B * L / 64, dm / 64, KS), blk, 0, stream>>>(
            yt, out_w, gpart, B * L, dm, di, KS);
        int slab = B * L * dm;                       // 2,097,152
        reduce_splitk<<<dim3((slab / 4 + 255) / 256, 1), blk, 0, stream>>>(
            gpart, out, slab, KS);
    }
}